// Round 1
// baseline (1045.005 us; speedup 1.0000x reference)
//
#include <hip/hip_runtime.h>
#include <math.h>

#define BATCH 36
#define H 8
#define L 1152
#define DK 72
#define DM 576
#define LK 128
#define B2 18
#define NC 3

// derived
#define POOL_PER_B (DM*LK)          // 73728
#define POOL_TOTAL (BATCH*POOL_PER_B) // 2654208
#define CLUS_TOTAL (BATCH*LK*B2)    // 82944
#define CCPOOL_PER_B (LK*B2*64)     // 147456
#define CTX_ELEMS (BATCH*H*L*DK)    // 23887872

// ---------------------------------------------------------------------------
// K1: MaxPool1d(kernel=9, stride=9, pad=4) on K,V viewed as (b, 576, 1152).
// Output layout (b, m, w) flat == (b, h, lk, d) flat after raw reshape.
// ---------------------------------------------------------------------------
__global__ __launch_bounds__(256) void pool_kernel(
    const float* __restrict__ Kin, const float* __restrict__ Vin,
    float* __restrict__ pK, float* __restrict__ pV) {
  int o = blockIdx.x * 256 + threadIdx.x;
  if (o >= POOL_TOTAL) return;
  int bb = o / POOL_PER_B;
  int j  = o % POOL_PER_B;
  int m  = j >> 7;       // /128
  int w  = j & 127;
  int t0 = w * 9 - 4;
  int lo = t0 < 0 ? 0 : t0;
  int hi = t0 + 8; if (hi > L - 1) hi = L - 1;
  const float* kin = Kin + (size_t)bb * (DM * L) + (size_t)m * L;
  const float* vin = Vin + (size_t)bb * (DM * L) + (size_t)m * L;
  float mk = -INFINITY, mv = -INFINITY;
  for (int t = lo; t <= hi; ++t) {
    mk = fmaxf(mk, kin[t]);
    mv = fmaxf(mv, vin[t]);
  }
  pK[o] = mk;
  pV[o] = mv;
}

// ---------------------------------------------------------------------------
// K2: per (bb, lk2, u2): gather the permuted 576-vector K_unf, dot with Wp
// (3 cols) + relu; then cluster_k = softmax(.@Wck+bck), cluster_q = softmax(
// .@Wcq+bcq). Store cq, ck. Accumulate log(softplus(std(cq, ddof=1))).
// Index math: flat f = lk2*10368 + u2*576 + m2 decomposes (per batch) as
// hh*165888 + lk*1296 + d*18 + u, with source batch kb = bb+u (zero if <18,
// else pooledK batch kb-17).
// ---------------------------------------------------------------------------
__global__ __launch_bounds__(256) void cluster_kernel(
    const float* __restrict__ pK,
    const float* __restrict__ Wp,  const float* __restrict__ bp,
    const float* __restrict__ Wck, const float* __restrict__ bck,
    const float* __restrict__ Wcq, const float* __restrict__ bcq,
    float* __restrict__ cq_out, float* __restrict__ ck_out,
    float* __restrict__ loss_acc) {
  int t   = blockIdx.x * 256 + threadIdx.x;     // exactly 82944
  int bb  = t / (LK * B2);
  int r   = t % (LK * B2);
  int lk2 = r / B2;
  int u2  = r % B2;

  int base = lk2 * 10368 + u2 * 576;
  int hh   = base / 165888;      // constant over the 576 block
  int fr   = base % 165888;      // multiple of 18

  const float* pKh = pK + hh * 9216;
  float a0 = 0.f, a1 = 0.f, a2 = 0.f;

  for (int g = 0; g < 32; ++g) {
    int lk  = fr / 1296;
    int d   = (fr - lk * 1296) / 18;
    int off = lk * 72 + d;
    const float* wp = Wp + g * 54;   // Wp[(g*18+u)*3 + c]
#pragma unroll
    for (int u = 0; u < B2; ++u) {
      int kb = bb + u;
      float v = (kb >= B2) ? pKh[(size_t)(kb - 17) * POOL_PER_B + off] : 0.f;
      a0 = fmaf(v, wp[u * 3 + 0], a0);
      a1 = fmaf(v, wp[u * 3 + 1], a1);
      a2 = fmaf(v, wp[u * 3 + 2], a2);
    }
    fr += 18;
  }

  float p0 = fmaxf(a0 + bp[0], 0.f);
  float p1 = fmaxf(a1 + bp[1], 0.f);
  float p2 = fmaxf(a2 + bp[2], 0.f);

  // cluster_k = softmax(p @ Wck + bck)   (Wck is (3,3) row-major)
  float k0 = p0 * Wck[0] + p1 * Wck[3] + p2 * Wck[6] + bck[0];
  float k1 = p0 * Wck[1] + p1 * Wck[4] + p2 * Wck[7] + bck[1];
  float k2 = p0 * Wck[2] + p1 * Wck[5] + p2 * Wck[8] + bck[2];
  float mk = fmaxf(k0, fmaxf(k1, k2));
  float e0 = __expf(k0 - mk), e1 = __expf(k1 - mk), e2 = __expf(k2 - mk);
  float inv = 1.f / (e0 + e1 + e2);
  float ck0 = e0 * inv, ck1 = e1 * inv, ck2 = e2 * inv;

  // cluster_q = softmax(p @ Wcq + bcq)
  float q0 = p0 * Wcq[0] + p1 * Wcq[3] + p2 * Wcq[6] + bcq[0];
  float q1 = p0 * Wcq[1] + p1 * Wcq[4] + p2 * Wcq[7] + bcq[1];
  float q2 = p0 * Wcq[2] + p1 * Wcq[5] + p2 * Wcq[8] + bcq[2];
  float mq = fmaxf(q0, fmaxf(q1, q2));
  float f0 = __expf(q0 - mq), f1 = __expf(q1 - mq), f2 = __expf(q2 - mq);
  float invq = 1.f / (f0 + f1 + f2);
  float cq0 = f0 * invq, cq1 = f1 * invq, cq2 = f2 * invq;

  ck_out[(size_t)t * 3 + 0] = ck0;
  ck_out[(size_t)t * 3 + 1] = ck1;
  ck_out[(size_t)t * 3 + 2] = ck2;
  cq_out[(size_t)t * 3 + 0] = cq0;
  cq_out[(size_t)t * 3 + 1] = cq1;
  cq_out[(size_t)t * 3 + 2] = cq2;

  // sigma = softplus(std(cq, ddof=1)); accumulate log(sigma)
  float mean = (cq0 + cq1 + cq2) * (1.f / 3.f);
  float d0 = cq0 - mean, d1 = cq1 - mean, d2 = cq2 - mean;
  float var = (d0 * d0 + d1 * d1 + d2 * d2) * 0.5f;
  float sd  = sqrtf(var);
  float sig = log1pf(__expf(sd));
  float ls  = logf(sig);

  __shared__ float red[256];
  red[threadIdx.x] = ls;
  __syncthreads();
  for (int s = 128; s > 0; s >>= 1) {
    if (threadIdx.x < s) red[threadIdx.x] += red[threadIdx.x + s];
    __syncthreads();
  }
  if (threadIdx.x == 0) atomicAdd(loss_acc, red[0]);
}

// ---------------------------------------------------------------------------
// K3: per (bb, lk2): causal 18x18 attention over cluster_q/cluster_k,
// cluster_q2 @ Wb + bias -> relu -> disjoint maxpool(9) -> ccpool flat
// (lk, p, w) per batch (== the order the final raw reshape consumes).
// ---------------------------------------------------------------------------
__global__ __launch_bounds__(256) void center_kernel(
    const float* __restrict__ cq, const float* __restrict__ ck,
    const float* __restrict__ Wb, const float* __restrict__ bbias,
    float* __restrict__ ccpool) {
  int blk = blockIdx.x;                // 4608
  int bb  = blk / LK;
  int lk2 = blk % LK;
  int tid = threadIdx.x;

  __shared__ float scq[54], sck[54], sq2[54];
  __shared__ float sWb[3 * 576];
  __shared__ float sbb[576];

  const float* cqb = cq + ((size_t)bb * (LK * B2) + (size_t)lk2 * B2) * 3;
  const float* ckb = ck + ((size_t)bb * (LK * B2) + (size_t)lk2 * B2) * 3;
  if (tid < 54) { scq[tid] = cqb[tid]; sck[tid] = ckb[tid]; }
  for (int i = tid; i < 1728; i += 256) sWb[i] = Wb[i];
  for (int i = tid; i < 576; i += 256) sbb[i] = bbias[i];
  __syncthreads();

  if (tid < B2) {
    int p = tid;
    float s[B2];
    float g0 = scq[p * 3 + 0], g1 = scq[p * 3 + 1], g2 = scq[p * 3 + 2];
    float mx = -INFINITY;
#pragma unroll
    for (int u = 0; u < B2; ++u) {
      float sv = (g0 * sck[u * 3] + g1 * sck[u * 3 + 1] + g2 * sck[u * 3 + 2]) *
                 (1.f / 3.f);
      if (u > p) sv = -1e9f;
      s[u] = sv;
      mx = fmaxf(mx, sv);
    }
    float sum = 0.f;
#pragma unroll
    for (int u = 0; u < B2; ++u) { s[u] = __expf(s[u] - mx); sum += s[u]; }
    float inv = 1.f / sum;
    float o0 = 0.f, o1 = 0.f, o2 = 0.f;
#pragma unroll
    for (int u = 0; u < B2; ++u) {
      float a = s[u] * inv;
      o0 = fmaf(a, scq[u * 3 + 0], o0);
      o1 = fmaf(a, scq[u * 3 + 1], o1);
      o2 = fmaf(a, scq[u * 3 + 2], o2);
    }
    sq2[p * 3 + 0] = o0; sq2[p * 3 + 1] = o1; sq2[p * 3 + 2] = o2;
  }
  __syncthreads();

  float* outb = ccpool + (size_t)bb * CCPOOL_PER_B + (size_t)lk2 * (B2 * 64);
  for (int i = tid; i < B2 * 64; i += 256) {
    int p = i >> 6;
    int w = i & 63;
    float g0 = sq2[p * 3 + 0], g1 = sq2[p * 3 + 1], g2 = sq2[p * 3 + 2];
    int t0 = w * 9 - 4;
    int lo = t0 < 0 ? 0 : t0;
    int hi = t0 + 8; if (hi > 575) hi = 575;
    float mxv = -INFINITY;
    for (int tt = lo; tt <= hi; ++tt) {
      float cv = g0 * sWb[tt] + g1 * sWb[576 + tt] + g2 * sWb[1152 + tt] + sbb[tt];
      cv = fmaxf(cv, 0.f);
      mxv = fmaxf(mxv, cv);
    }
    outb[i] = mxv;
  }
}

// ---------------------------------------------------------------------------
// K4: fused second attention. Per (b,h): Csum[k][d] = ccpool half0 + half1
// (both contiguous), staged in LDS with Vp. One q-row per thread, online
// softmax over 128 keys, context = attn @ Vp.
// ---------------------------------------------------------------------------
__global__ __launch_bounds__(128) void attn_kernel(
    const float* __restrict__ Q, const float* __restrict__ ccpool,
    const float* __restrict__ pV, float* __restrict__ out) {
  __shared__ __align__(16) float cs[LK * DK];   // 9216
  __shared__ __align__(16) float vv[LK * DK];   // 9216

  int bh = blockIdx.x / 9;
  int qt = blockIdx.x % 9;
  int bb = bh / H, hh = bh % H;

  const float* cp = ccpool + (size_t)bb * CCPOOL_PER_B + (size_t)hh * 18432;
  const float* vp = pV + (size_t)bh * (LK * DK);
  for (int i = threadIdx.x; i < LK * DK; i += 128) {
    cs[i] = cp[i] + cp[9216 + i];
    vv[i] = vp[i];
  }
  __syncthreads();

  int q = qt * 128 + threadIdx.x;   // < 1152 always
  const float4* qp = (const float4*)(Q + ((size_t)bh * L + q) * DK);
  float4 qr[18];
#pragma unroll
  for (int j = 0; j < 18; ++j) qr[j] = qp[j];

  float m = -INFINITY, l = 0.f;
  float4 av[18];
#pragma unroll
  for (int j = 0; j < 18; ++j) av[j] = make_float4(0.f, 0.f, 0.f, 0.f);

  for (int k = 0; k < LK; ++k) {
    const float4* c4 = (const float4*)&cs[k * DK];
    float s = 0.f;
#pragma unroll
    for (int j = 0; j < 18; ++j) {
      float4 cc = c4[j];
      s = fmaf(qr[j].x, cc.x, s);
      s = fmaf(qr[j].y, cc.y, s);
      s = fmaf(qr[j].z, cc.z, s);
      s = fmaf(qr[j].w, cc.w, s);
    }
    if (s > m) {
      float sc = __expf(m - s);   // exp(-inf)=0 on first hit
      l *= sc;
#pragma unroll
      for (int j = 0; j < 18; ++j) {
        av[j].x *= sc; av[j].y *= sc; av[j].z *= sc; av[j].w *= sc;
      }
      m = s;
    }
    float p = __expf(s - m);
    l += p;
    const float4* v4 = (const float4*)&vv[k * DK];
#pragma unroll
    for (int j = 0; j < 18; ++j) {
      float4 vc = v4[j];
      av[j].x = fmaf(p, vc.x, av[j].x);
      av[j].y = fmaf(p, vc.y, av[j].y);
      av[j].z = fmaf(p, vc.z, av[j].z);
      av[j].w = fmaf(p, vc.w, av[j].w);
    }
  }
  float inv = 1.f / l;
  float4* op = (float4*)(out + ((size_t)bh * L + q) * DK);
#pragma unroll
  for (int j = 0; j < 18; ++j) {
    op[j] = make_float4(av[j].x * inv, av[j].y * inv, av[j].z * inv, av[j].w * inv);
  }
}

// ---------------------------------------------------------------------------
// K5: finalize loss. mu == xk == 1/3 exactly => (xk-mu)^2 term vanishes and
// ce == (128/3)*ln(128) is constant. loss = mean(log sigma) + 0.5*ln(2pi) + ce.
// ---------------------------------------------------------------------------
__global__ void finalize_kernel(const float* __restrict__ loss_acc,
                                float* __restrict__ out_loss) {
  // 207.019957927237 (ce) + 0.918938533205 (0.5*ln(2*pi))
  *out_loss = loss_acc[0] * (1.f / 82944.f) + 207.93889646f;
}

extern "C" void kernel_launch(void* const* d_in, const int* in_sizes, int n_in,
                              void* d_out, int out_size, void* d_ws, size_t ws_size,
                              hipStream_t stream) {
  const float* Q    = (const float*)d_in[0];
  const float* Kin  = (const float*)d_in[1];
  const float* Vin  = (const float*)d_in[2];
  const float* Wp   = (const float*)d_in[3];
  const float* bp   = (const float*)d_in[4];
  const float* Wck  = (const float*)d_in[5];
  const float* bck  = (const float*)d_in[6];
  const float* Wcq  = (const float*)d_in[7];
  const float* bcq  = (const float*)d_in[8];
  const float* Wb   = (const float*)d_in[9];
  const float* bbv  = (const float*)d_in[10];
  float* out = (float*)d_out;

  float* ws = (float*)d_ws;
  float* pK       = ws;                      // 2654208
  float* pV       = pK + POOL_TOTAL;         // 2654208
  float* cq       = pV + POOL_TOTAL;         // 248832
  float* ck       = cq + (size_t)CLUS_TOTAL * 3;
  float* ccpool   = ck + (size_t)CLUS_TOTAL * 3;   // 5308416
  float* loss_acc = ccpool + (size_t)BATCH * CCPOOL_PER_B;

  hipMemsetAsync(loss_acc, 0, sizeof(float), stream);

  pool_kernel<<<POOL_TOTAL / 256, 256, 0, stream>>>(Kin, Vin, pK, pV);
  cluster_kernel<<<CLUS_TOTAL / 256, 256, 0, stream>>>(
      pK, Wp, bp, Wck, bck, Wcq, bcq, cq, ck, loss_acc);
  center_kernel<<<BATCH * LK, 256, 0, stream>>>(cq, ck, Wb, bbv, ccpool);
  attn_kernel<<<BATCH * H * 9, 128, 0, stream>>>(Q, ccpool, pV, out);
  finalize_kernel<<<1, 1, 0, stream>>>(loss_acc, out + CTX_ELEMS);
}

// Round 2
// 636.817 us; speedup vs baseline: 1.6410x; 1.6410x over previous
//
#include <hip/hip_runtime.h>
#include <math.h>

#define BATCH 36
#define H 8
#define L 1152
#define DK 72
#define DM 576
#define LK 128
#define B2 18
#define NC 3

// derived
#define POOL_PER_B (DM*LK)            // 73728
#define POOL_TOTAL (BATCH*POOL_PER_B) // 2654208
#define CLUS_TOTAL (BATCH*LK*B2)      // 82944
#define CCPOOL_PER_B (LK*B2*64)       // 147456
#define CTX_ELEMS (BATCH*H*L*DK)      // 23887872
#define NBH (BATCH*H)                 // 288

typedef __attribute__((ext_vector_type(8))) short short8;
typedef __attribute__((ext_vector_type(4))) float f32x4;

// round-to-nearest-even fp32 -> bf16 bits
__device__ __forceinline__ unsigned short bf16_rne(float x) {
  unsigned u = __float_as_uint(x);
  unsigned r = u + 0x7FFFu + ((u >> 16) & 1u);
  return (unsigned short)(r >> 16);
}
__device__ __forceinline__ void split_hl(float x, unsigned short& h, unsigned short& l) {
  h = bf16_rne(x);
  float fh = __uint_as_float(((unsigned)h) << 16);
  l = bf16_rne(x - fh);
}
__device__ __forceinline__ unsigned pack2(float a, float b) {
  return (unsigned)bf16_rne(a) | ((unsigned)bf16_rne(b) << 16);
}

// ---------------------------------------------------------------------------
// K1: MaxPool1d(kernel=9, stride=9, pad=4) on K,V viewed as (b, 576, 1152).
// Output layout (b, m, w) flat == (b, h, lk, d) flat after raw reshape.
// ---------------------------------------------------------------------------
__global__ __launch_bounds__(256) void pool_kernel(
    const float* __restrict__ Kin, const float* __restrict__ Vin,
    float* __restrict__ pK, float* __restrict__ pV) {
  int o = blockIdx.x * 256 + threadIdx.x;
  if (o >= POOL_TOTAL) return;
  int bb = o / POOL_PER_B;
  int j  = o % POOL_PER_B;
  int m  = j >> 7;
  int w  = j & 127;
  int t0 = w * 9 - 4;
  int lo = t0 < 0 ? 0 : t0;
  int hi = t0 + 8; if (hi > L - 1) hi = L - 1;
  const float* kin = Kin + (size_t)bb * (DM * L) + (size_t)m * L;
  const float* vin = Vin + (size_t)bb * (DM * L) + (size_t)m * L;
  float mk = -INFINITY, mv = -INFINITY;
  for (int t = lo; t <= hi; ++t) {
    mk = fmaxf(mk, kin[t]);
    mv = fmaxf(mv, vin[t]);
  }
  pK[o] = mk;
  pV[o] = mv;
}

// ---------------------------------------------------------------------------
// K2: clustering head (see round-1 notes for the index algebra).
// ---------------------------------------------------------------------------
__global__ __launch_bounds__(256) void cluster_kernel(
    const float* __restrict__ pK,
    const float* __restrict__ Wp,  const float* __restrict__ bp,
    const float* __restrict__ Wck, const float* __restrict__ bck,
    const float* __restrict__ Wcq, const float* __restrict__ bcq,
    float* __restrict__ cq_out, float* __restrict__ ck_out,
    float* __restrict__ loss_acc) {
  int t   = blockIdx.x * 256 + threadIdx.x;
  int bb  = t / (LK * B2);
  int r   = t % (LK * B2);
  int lk2 = r / B2;
  int u2  = r % B2;

  int base = lk2 * 10368 + u2 * 576;
  int hh   = base / 165888;
  int fr   = base % 165888;

  const float* pKh = pK + hh * 9216;
  float a0 = 0.f, a1 = 0.f, a2 = 0.f;

  for (int g = 0; g < 32; ++g) {
    int lk  = fr / 1296;
    int d   = (fr - lk * 1296) / 18;
    int off = lk * 72 + d;
    const float* wp = Wp + g * 54;
#pragma unroll
    for (int u = 0; u < B2; ++u) {
      int kb = bb + u;
      float v = (kb >= B2) ? pKh[(size_t)(kb - 17) * POOL_PER_B + off] : 0.f;
      a0 = fmaf(v, wp[u * 3 + 0], a0);
      a1 = fmaf(v, wp[u * 3 + 1], a1);
      a2 = fmaf(v, wp[u * 3 + 2], a2);
    }
    fr += 18;
  }

  float p0 = fmaxf(a0 + bp[0], 0.f);
  float p1 = fmaxf(a1 + bp[1], 0.f);
  float p2 = fmaxf(a2 + bp[2], 0.f);

  float k0 = p0 * Wck[0] + p1 * Wck[3] + p2 * Wck[6] + bck[0];
  float k1 = p0 * Wck[1] + p1 * Wck[4] + p2 * Wck[7] + bck[1];
  float k2 = p0 * Wck[2] + p1 * Wck[5] + p2 * Wck[8] + bck[2];
  float mk = fmaxf(k0, fmaxf(k1, k2));
  float e0 = __expf(k0 - mk), e1 = __expf(k1 - mk), e2 = __expf(k2 - mk);
  float inv = 1.f / (e0 + e1 + e2);
  float ck0 = e0 * inv, ck1 = e1 * inv, ck2 = e2 * inv;

  float q0 = p0 * Wcq[0] + p1 * Wcq[3] + p2 * Wcq[6] + bcq[0];
  float q1 = p0 * Wcq[1] + p1 * Wcq[4] + p2 * Wcq[7] + bcq[1];
  float q2 = p0 * Wcq[2] + p1 * Wcq[5] + p2 * Wcq[8] + bcq[2];
  float mq = fmaxf(q0, fmaxf(q1, q2));
  float f0 = __expf(q0 - mq), f1 = __expf(q1 - mq), f2 = __expf(q2 - mq);
  float invq = 1.f / (f0 + f1 + f2);
  float cq0 = f0 * invq, cq1 = f1 * invq, cq2 = f2 * invq;

  ck_out[(size_t)t * 3 + 0] = ck0;
  ck_out[(size_t)t * 3 + 1] = ck1;
  ck_out[(size_t)t * 3 + 2] = ck2;
  cq_out[(size_t)t * 3 + 0] = cq0;
  cq_out[(size_t)t * 3 + 1] = cq1;
  cq_out[(size_t)t * 3 + 2] = cq2;

  float mean = (cq0 + cq1 + cq2) * (1.f / 3.f);
  float d0 = cq0 - mean, d1 = cq1 - mean, d2 = cq2 - mean;
  float var = (d0 * d0 + d1 * d1 + d2 * d2) * 0.5f;
  float sd  = sqrtf(var);
  float sig = log1pf(__expf(sd));
  float ls  = logf(sig);

  __shared__ float red[256];
  red[threadIdx.x] = ls;
  __syncthreads();
  for (int s = 128; s > 0; s >>= 1) {
    if (threadIdx.x < s) red[threadIdx.x] += red[threadIdx.x + s];
    __syncthreads();
  }
  if (threadIdx.x == 0) atomicAdd(loss_acc, red[0]);
}

// ---------------------------------------------------------------------------
// K3: per (bb, lk2): causal 18x18 attention over cluster_q/cluster_k,
// cluster_q2 @ Wb + bias -> relu -> disjoint maxpool(9) -> ccpool.
// ---------------------------------------------------------------------------
__global__ __launch_bounds__(256) void center_kernel(
    const float* __restrict__ cq, const float* __restrict__ ck,
    const float* __restrict__ Wb, const float* __restrict__ bbias,
    float* __restrict__ ccpool) {
  int blk = blockIdx.x;
  int bb  = blk / LK;
  int lk2 = blk % LK;
  int tid = threadIdx.x;

  __shared__ float scq[54], sck[54], sq2[54];
  __shared__ float sWb[3 * 576];
  __shared__ float sbb[576];

  const float* cqb = cq + ((size_t)bb * (LK * B2) + (size_t)lk2 * B2) * 3;
  const float* ckb = ck + ((size_t)bb * (LK * B2) + (size_t)lk2 * B2) * 3;
  if (tid < 54) { scq[tid] = cqb[tid]; sck[tid] = ckb[tid]; }
  for (int i = tid; i < 1728; i += 256) sWb[i] = Wb[i];
  for (int i = tid; i < 576; i += 256) sbb[i] = bbias[i];
  __syncthreads();

  if (tid < B2) {
    int p = tid;
    float s[B2];
    float g0 = scq[p * 3 + 0], g1 = scq[p * 3 + 1], g2 = scq[p * 3 + 2];
    float mx = -INFINITY;
#pragma unroll
    for (int u = 0; u < B2; ++u) {
      float sv = (g0 * sck[u * 3] + g1 * sck[u * 3 + 1] + g2 * sck[u * 3 + 2]) *
                 (1.f / 3.f);
      if (u > p) sv = -1e9f;
      s[u] = sv;
      mx = fmaxf(mx, sv);
    }
    float sum = 0.f;
#pragma unroll
    for (int u = 0; u < B2; ++u) { s[u] = __expf(s[u] - mx); sum += s[u]; }
    float inv = 1.f / sum;
    float o0 = 0.f, o1 = 0.f, o2 = 0.f;
#pragma unroll
    for (int u = 0; u < B2; ++u) {
      float a = s[u] * inv;
      o0 = fmaf(a, scq[u * 3 + 0], o0);
      o1 = fmaf(a, scq[u * 3 + 1], o1);
      o2 = fmaf(a, scq[u * 3 + 2], o2);
    }
    sq2[p * 3 + 0] = o0; sq2[p * 3 + 1] = o1; sq2[p * 3 + 2] = o2;
  }
  __syncthreads();

  float* outb = ccpool + (size_t)bb * CCPOOL_PER_B + (size_t)lk2 * (B2 * 64);
  for (int i = tid; i < B2 * 64; i += 256) {
    int p = i >> 6;
    int w = i & 63;
    float g0 = sq2[p * 3 + 0], g1 = sq2[p * 3 + 1], g2 = sq2[p * 3 + 2];
    int t0 = w * 9 - 4;
    int lo = t0 < 0 ? 0 : t0;
    int hi = t0 + 8; if (hi > 575) hi = 575;
    float mxv = -INFINITY;
    for (int tt = lo; tt <= hi; ++tt) {
      float cv = g0 * sWb[tt] + g1 * sWb[576 + tt] + g2 * sWb[1152 + tt] + sbb[tt];
      cv = fmaxf(cv, 0.f);
      mxv = fmaxf(mxv, cv);
    }
    outb[i] = mxv;
  }
}

// ---------------------------------------------------------------------------
// K4a: prep MFMA operand fragments.
// Cfrag (A of S^T = Csum * Q^T): t = ((bh*8+mt)*3+ks)*64+lane -> 2x uint4
//   value j: key = mt*16+(lane&15), d = ks*32+(lane>>4)*8+j (0 if d>=72)
//   hi/lo bf16 split of Csum[bh][key][d].
// Vfrag (B of O = P * V): t2 = ((bh*5+nt)*4+ks)*64+lane -> 2x uint4
//   value j: d = nt*16+(lane&15), k = ks*32+(lane>>4)*8+j (0 if d>=72)
//   hi/lo bf16 split of Vp[bh][k][d].
// ---------------------------------------------------------------------------
#define CFRAG_T (NBH*8*3*64)   // 442368
#define VFRAG_T (NBH*5*4*64)   // 368640
__global__ __launch_bounds__(256) void prep_kernel(
    const float* __restrict__ ccpool, const float* __restrict__ pV,
    uint4* __restrict__ Cfrag, uint4* __restrict__ Vfrag) {
  int t = blockIdx.x * 256 + threadIdx.x;   // 811008 exactly
  unsigned short hi[8], lo[8];
  if (t < CFRAG_T) {
    int lane = t & 63;
    int rest = t >> 6;            // (bh*8+mt)*3+ks
    int ks = rest % 3;
    int mtb = rest / 3;
    int mt = mtb & 7;
    int bh = mtb >> 3;
    int bb = bh >> 3, hh = bh & 7;
    int key = mt * 16 + (lane & 15);
    int d0 = ks * 32 + (lane >> 4) * 8;
    const float* cp = ccpool + (size_t)bb * CCPOOL_PER_B + hh * 18432 + key * 72;
#pragma unroll
    for (int j = 0; j < 8; ++j) {
      int d = d0 + j;
      float v = (d < 72) ? (cp[d] + cp[9216 + d]) : 0.f;
      split_hl(v, hi[j], lo[j]);
    }
    uint4 h4, l4;
    h4.x = hi[0] | (hi[1] << 16); h4.y = hi[2] | (hi[3] << 16);
    h4.z = hi[4] | (hi[5] << 16); h4.w = hi[6] | (hi[7] << 16);
    l4.x = lo[0] | (lo[1] << 16); l4.y = lo[2] | (lo[3] << 16);
    l4.z = lo[4] | (lo[5] << 16); l4.w = lo[6] | (lo[7] << 16);
    Cfrag[(size_t)t * 2 + 0] = h4;
    Cfrag[(size_t)t * 2 + 1] = l4;
  } else {
    int t2 = t - CFRAG_T;
    int lane = t2 & 63;
    int rest = t2 >> 6;           // (bh*5+nt)*4+ks
    int ks = rest & 3;
    int ntb = rest >> 2;
    int nt = ntb % 5;
    int bh = ntb / 5;
    int d = nt * 16 + (lane & 15);
    int k0 = ks * 32 + (lane >> 4) * 8;
    const float* vp = pV + (size_t)bh * (LK * DK);
#pragma unroll
    for (int j = 0; j < 8; ++j) {
      int k = k0 + j;
      float v = (d < 72) ? vp[k * 72 + d] : 0.f;
      split_hl(v, hi[j], lo[j]);
    }
    uint4 h4, l4;
    h4.x = hi[0] | (hi[1] << 16); h4.y = hi[2] | (hi[3] << 16);
    h4.z = hi[4] | (hi[5] << 16); h4.w = hi[6] | (hi[7] << 16);
    l4.x = lo[0] | (lo[1] << 16); l4.y = lo[2] | (lo[3] << 16);
    l4.z = lo[4] | (lo[5] << 16); l4.w = lo[6] | (lo[7] << 16);
    Vfrag[(size_t)t2 * 2 + 0] = h4;
    Vfrag[(size_t)t2 * 2 + 1] = l4;
  }
}

// ---------------------------------------------------------------------------
// K4b: MFMA attention. Block = 4 waves; wave handles 32 q rows (2 subtiles of
// 16). S^T = Csum*Q^T via mfma_f32_16x16x32_bf16 with hi/lo split (3 mfma per
// step). In-register softmax (S^T: row=key, col=q -> per-q reduce = 32 local
// + shfl_xor 16/32). Normalized P -> bf16 -> XOR-swizzled LDS -> A-fragment
// reads for O = P*(Vhi+Vlo).
// ---------------------------------------------------------------------------
__global__ __launch_bounds__(256) void attn2_kernel(
    const float* __restrict__ Q, const uint4* __restrict__ Cfrag,
    const uint4* __restrict__ Vfrag, float* __restrict__ out) {
  // per wave: 32 rows(q) x 136 keys-pad of bf16 = 8704 B
  __shared__ __align__(16) char Plds[4][32 * 272];

  int bh = blockIdx.x / 9, qt = blockIdx.x % 9;
  int wid = threadIdx.x >> 6, lane = threadIdx.x & 63;
  int lq = lane & 15, lg = lane >> 4;
  int qbase = qt * 128 + wid * 32;

  f32x4 sacc[2][8];
#pragma unroll
  for (int s = 0; s < 2; ++s)
#pragma unroll
    for (int mt = 0; mt < 8; ++mt) sacc[s][mt] = (f32x4){0.f, 0.f, 0.f, 0.f};

  // ---- S^T = C * Q^T ----
#pragma unroll
  for (int ks = 0; ks < 3; ++ks) {
    short8 qh[2], ql[2];
#pragma unroll
    for (int s = 0; s < 2; ++s) {
      int q = qbase + s * 16 + lq;
      const float* qrow = Q + ((size_t)bh * L + q) * DK;
      int d0 = ks * 32 + lg * 8;
      float x[8];
      if (ks < 2) {
        float4 a = *(const float4*)(qrow + d0);
        float4 b = *(const float4*)(qrow + d0 + 4);
        x[0] = a.x; x[1] = a.y; x[2] = a.z; x[3] = a.w;
        x[4] = b.x; x[5] = b.y; x[6] = b.z; x[7] = b.w;
      } else {
        if (lg == 0) {
          float4 a = *(const float4*)(qrow + 64);
          float4 b = *(const float4*)(qrow + 68);
          x[0] = a.x; x[1] = a.y; x[2] = a.z; x[3] = a.w;
          x[4] = b.x; x[5] = b.y; x[6] = b.z; x[7] = b.w;
        } else {
#pragma unroll
          for (int j = 0; j < 8; ++j) x[j] = 0.f;
        }
      }
#pragma unroll
      for (int j = 0; j < 8; ++j) {
        unsigned short h, l2;
        split_hl(x[j], h, l2);
        qh[s][j] = (short)h;
        ql[s][j] = (short)l2;
      }
    }
#pragma unroll
    for (int mt = 0; mt < 8; ++mt) {
      const short8* cp8 = (const short8*)(Cfrag +
          ((((size_t)bh * 8 + mt) * 3 + ks) * 64 + lane) * 2);
      short8 chi = cp8[0];
      short8 clo = cp8[1];
#pragma unroll
      for (int s = 0; s < 2; ++s) {
        sacc[s][mt] = __builtin_amdgcn_mfma_f32_16x16x32_bf16(chi, qh[s], sacc[s][mt], 0, 0, 0);
        sacc[s][mt] = __builtin_amdgcn_mfma_f32_16x16x32_bf16(chi, ql[s], sacc[s][mt], 0, 0, 0);
        sacc[s][mt] = __builtin_amdgcn_mfma_f32_16x16x32_bf16(clo, qh[s], sacc[s][mt], 0, 0, 0);
      }
    }
  }

  // ---- softmax over keys (per q-col) + P -> bf16 -> LDS ----
  char* pb = Plds[wid];
#pragma unroll
  for (int s = 0; s < 2; ++s) {
    float mx = -INFINITY;
#pragma unroll
    for (int mt = 0; mt < 8; ++mt)
#pragma unroll
      for (int r = 0; r < 4; ++r) mx = fmaxf(mx, sacc[s][mt][r]);
    mx = fmaxf(mx, __shfl_xor(mx, 16));
    mx = fmaxf(mx, __shfl_xor(mx, 32));
    float sum = 0.f;
#pragma unroll
    for (int mt = 0; mt < 8; ++mt)
#pragma unroll
      for (int r = 0; r < 4; ++r) {
        float p = __expf(sacc[s][mt][r] - mx);
        sacc[s][mt][r] = p;
        sum += p;
      }
    sum += __shfl_xor(sum, 16);
    sum += __shfl_xor(sum, 32);
    float inv = 1.f / sum;
    int row = s * 16 + lq;
    unsigned roff = row * 272;
    unsigned sw = (unsigned)((row & 7) << 4);
#pragma unroll
    for (int mt = 0; mt < 8; ++mt) {
      unsigned w0 = pack2(sacc[s][mt][0] * inv, sacc[s][mt][1] * inv);
      unsigned w1 = pack2(sacc[s][mt][2] * inv, sacc[s][mt][3] * inv);
      unsigned off = (roff + mt * 32 + lg * 8) ^ sw;
      *(uint2*)(pb + off) = make_uint2(w0, w1);
    }
  }

  // ---- O = P * V ----
  f32x4 oacc[2][5];
#pragma unroll
  for (int s = 0; s < 2; ++s)
#pragma unroll
    for (int nt = 0; nt < 5; ++nt) oacc[s][nt] = (f32x4){0.f, 0.f, 0.f, 0.f};

#pragma unroll
  for (int ks = 0; ks < 4; ++ks) {
    short8 pa[2];
#pragma unroll
    for (int s = 0; s < 2; ++s) {
      int row = s * 16 + lq;
      unsigned off = ((unsigned)row * 272 + ks * 64 + lg * 16) ^
                     (unsigned)((row & 7) << 4);
      pa[s] = *(const short8*)(pb + off);
    }
#pragma unroll
    for (int nt = 0; nt < 5; ++nt) {
      const short8* vp8 = (const short8*)(Vfrag +
          ((((size_t)bh * 5 + nt) * 4 + ks) * 64 + lane) * 2);
      short8 vhi = vp8[0];
      short8 vlo = vp8[1];
#pragma unroll
      for (int s = 0; s < 2; ++s) {
        oacc[s][nt] = __builtin_amdgcn_mfma_f32_16x16x32_bf16(pa[s], vhi, oacc[s][nt], 0, 0, 0);
        oacc[s][nt] = __builtin_amdgcn_mfma_f32_16x16x32_bf16(pa[s], vlo, oacc[s][nt], 0, 0, 0);
      }
    }
  }

  // ---- store: D layout col=lane&15 (d), row=(lane>>4)*4+r (q) ----
#pragma unroll
  for (int s = 0; s < 2; ++s) {
#pragma unroll
    for (int nt = 0; nt < 5; ++nt) {
      int d = nt * 16 + lq;
      if (d < 72) {
        float* orow = out + ((size_t)bh * L + qbase + s * 16 + lg * 4) * DK + d;
#pragma unroll
        for (int r = 0; r < 4; ++r) orow[(size_t)r * DK] = oacc[s][nt][r];
      }
    }
  }
}

// ---------------------------------------------------------------------------
// K5: finalize loss. mu == xk == 1/3 exactly => gaussian term reduces and
// ce == (128/3)*ln(128) is constant.
// ---------------------------------------------------------------------------
__global__ void finalize_kernel(const float* __restrict__ loss_acc,
                                float* __restrict__ out_loss) {
  *out_loss = loss_acc[0] * (1.f / 82944.f) + 207.93889646f;
}

extern "C" void kernel_launch(void* const* d_in, const int* in_sizes, int n_in,
                              void* d_out, int out_size, void* d_ws, size_t ws_size,
                              hipStream_t stream) {
  const float* Q    = (const float*)d_in[0];
  const float* Kin  = (const float*)d_in[1];
  const float* Vin  = (const float*)d_in[2];
  const float* Wp   = (const float*)d_in[3];
  const float* bp   = (const float*)d_in[4];
  const float* Wck  = (const float*)d_in[5];
  const float* bck  = (const float*)d_in[6];
  const float* Wcq  = (const float*)d_in[7];
  const float* bcq  = (const float*)d_in[8];
  const float* Wb   = (const float*)d_in[9];
  const float* bbv  = (const float*)d_in[10];
  float* out = (float*)d_out;

  float* ws = (float*)d_ws;
  float* pK       = ws;
  float* pV       = pK + POOL_TOTAL;
  float* cq       = pV + POOL_TOTAL;
  float* ck       = cq + (size_t)CLUS_TOTAL * 3;
  float* ccpool   = ck + (size_t)CLUS_TOTAL * 3;
  float* cfrag_f  = ccpool + (size_t)BATCH * CCPOOL_PER_B;
  uint4* Cfrag    = (uint4*)cfrag_f;                      // 884736 uint4
  uint4* Vfrag    = Cfrag + (size_t)CFRAG_T * 2;          // 737280 uint4
  float* loss_acc = (float*)(Vfrag + (size_t)VFRAG_T * 2);

  hipMemsetAsync(loss_acc, 0, sizeof(float), stream);

  pool_kernel<<<POOL_TOTAL / 256, 256, 0, stream>>>(Kin, Vin, pK, pV);
  cluster_kernel<<<CLUS_TOTAL / 256, 256, 0, stream>>>(
      pK, Wp, bp, Wck, bck, Wcq, bcq, cq, ck, loss_acc);
  center_kernel<<<BATCH * LK, 256, 0, stream>>>(cq, ck, Wb, bbv, ccpool);
  prep_kernel<<<(CFRAG_T + VFRAG_T) / 256, 256, 0, stream>>>(ccpool, pV, Cfrag, Vfrag);
  attn2_kernel<<<NBH * 9, 256, 0, stream>>>(Q, Cfrag, Vfrag, out);
  finalize_kernel<<<1, 1, 0, stream>>>(loss_acc, out + CTX_ELEMS);
}

// Round 3
// 265.662 us; speedup vs baseline: 3.9336x; 2.3971x over previous
//
#include <hip/hip_runtime.h>
#include <math.h>

#define BATCH 36
#define H 8
#define L 1152
#define DK 72
#define DM 576
#define LK 128
#define B2 18
#define NC 3

// derived
#define POOL_PER_B (DM*LK)            // 73728
#define POOL_TOTAL (BATCH*POOL_PER_B) // 2654208
#define CLUS_TOTAL (BATCH*LK*B2)      // 82944
#define CCPOOL_PER_B (LK*B2*64)       // 147456
#define CTX_ELEMS (BATCH*H*L*DK)      // 23887872
#define NBH (BATCH*H)                 // 288

typedef __attribute__((ext_vector_type(8))) short short8;
typedef __attribute__((ext_vector_type(4))) float f32x4;

// round-to-nearest-even fp32 -> bf16 bits
__device__ __forceinline__ unsigned short bf16_rne(float x) {
  unsigned u = __float_as_uint(x);
  unsigned r = u + 0x7FFFu + ((u >> 16) & 1u);
  return (unsigned short)(r >> 16);
}
__device__ __forceinline__ void split_hl(float x, unsigned short& h, unsigned short& l) {
  h = bf16_rne(x);
  float fh = __uint_as_float(((unsigned)h) << 16);
  l = bf16_rne(x - fh);
}
__device__ __forceinline__ unsigned pack2(float a, float b) {
  return (unsigned)bf16_rne(a) | ((unsigned)bf16_rne(b) << 16);
}

// ---------------------------------------------------------------------------
// K1: MaxPool1d(kernel=9, stride=9, pad=4) on K,V viewed as (b, 576, 1152).
// ---------------------------------------------------------------------------
__global__ __launch_bounds__(256) void pool_kernel(
    const float* __restrict__ Kin, const float* __restrict__ Vin,
    float* __restrict__ pK, float* __restrict__ pV) {
  int o = blockIdx.x * 256 + threadIdx.x;
  if (o >= POOL_TOTAL) return;
  int bb = o / POOL_PER_B;
  int j  = o % POOL_PER_B;
  int m  = j >> 7;
  int w  = j & 127;
  int t0 = w * 9 - 4;
  int lo = t0 < 0 ? 0 : t0;
  int hi = t0 + 8; if (hi > L - 1) hi = L - 1;
  const float* kin = Kin + (size_t)bb * (DM * L) + (size_t)m * L;
  const float* vin = Vin + (size_t)bb * (DM * L) + (size_t)m * L;
  float mk = -INFINITY, mv = -INFINITY;
  for (int t = lo; t <= hi; ++t) {
    mk = fmaxf(mk, kin[t]);
    mv = fmaxf(mv, vin[t]);
  }
  pK[o] = mk;
  pV[o] = mv;
}

// ---------------------------------------------------------------------------
// K2: clustering head, rewritten with the identity-gather insight:
//   cluster_k_p[bb][j2][c] = sum_{u,g} pK[bb+u-17][j2*32+g] * Wp[(g*18+u)*3+c]
// Block = (bb, 256-wide j2 slice); per tap u the 32KB contiguous pK slice is
// staged coalesced into LDS (row stride 33 floats: conflict-free on both the
// strided float4 writes (2-way max) and per-thread row reads ((tid+g)%32)).
// ---------------------------------------------------------------------------
__global__ __launch_bounds__(256) void cluster_kernel(
    const float* __restrict__ pK,
    const float* __restrict__ Wp,  const float* __restrict__ bp,
    const float* __restrict__ Wck, const float* __restrict__ bck,
    const float* __restrict__ Wcq, const float* __restrict__ bcq,
    float* __restrict__ cq_out, float* __restrict__ ck_out,
    float* __restrict__ loss_acc) {
  int bb = blockIdx.x / 9;
  int s  = blockIdx.x % 9;      // j2 slice [s*256, s*256+256)
  int tid = threadIdx.x;

  __shared__ float sK[256 * 33];     // padded rows
  __shared__ float sWp[1728];
  __shared__ float red[256];

  for (int i = tid; i < 1728; i += 256) sWp[i] = Wp[i];

  float a0 = 0.f, a1 = 0.f, a2 = 0.f;
  int umin = (bb >= 18) ? 0 : (18 - bb);

  for (int u = umin; u < 18; ++u) {
    int b2 = bb + u - 17;            // source pooled batch, >= 1
    __syncthreads();
    const float4* src = (const float4*)(pK + (size_t)b2 * POOL_PER_B + s * 8192);
#pragma unroll
    for (int k = 0; k < 8; ++k) {
      int i = tid + k * 256;
      float4 v = src[i];
      int base = i * 4;
      float* dst = &sK[(base >> 5) * 33 + (base & 31)];
      dst[0] = v.x; dst[1] = v.y; dst[2] = v.z; dst[3] = v.w;
    }
    __syncthreads();
    const float* wrow = &sWp[u * 3];   // + g*54 + c
    const float* krow = &sK[tid * 33];
#pragma unroll
    for (int g = 0; g < 32; ++g) {
      float v = krow[g];
      a0 = fmaf(v, wrow[g * 54 + 0], a0);
      a1 = fmaf(v, wrow[g * 54 + 1], a1);
      a2 = fmaf(v, wrow[g * 54 + 2], a2);
    }
  }

  // epilogue: relu -> two softmax3 -> store; loss partial
  float p0 = fmaxf(a0 + bp[0], 0.f);
  float p1 = fmaxf(a1 + bp[1], 0.f);
  float p2 = fmaxf(a2 + bp[2], 0.f);

  float k0 = p0 * Wck[0] + p1 * Wck[3] + p2 * Wck[6] + bck[0];
  float k1 = p0 * Wck[1] + p1 * Wck[4] + p2 * Wck[7] + bck[1];
  float k2 = p0 * Wck[2] + p1 * Wck[5] + p2 * Wck[8] + bck[2];
  float mk = fmaxf(k0, fmaxf(k1, k2));
  float e0 = __expf(k0 - mk), e1 = __expf(k1 - mk), e2 = __expf(k2 - mk);
  float inv = 1.f / (e0 + e1 + e2);
  float ck0 = e0 * inv, ck1 = e1 * inv, ck2 = e2 * inv;

  float q0 = p0 * Wcq[0] + p1 * Wcq[3] + p2 * Wcq[6] + bcq[0];
  float q1 = p0 * Wcq[1] + p1 * Wcq[4] + p2 * Wcq[7] + bcq[1];
  float q2 = p0 * Wcq[2] + p1 * Wcq[5] + p2 * Wcq[8] + bcq[2];
  float mq = fmaxf(q0, fmaxf(q1, q2));
  float f0 = __expf(q0 - mq), f1 = __expf(q1 - mq), f2 = __expf(q2 - mq);
  float invq = 1.f / (f0 + f1 + f2);
  float cq0 = f0 * invq, cq1 = f1 * invq, cq2 = f2 * invq;

  size_t t = (size_t)bb * 2304 + s * 256 + tid;   // == bb*2304 + j2
  ck_out[t * 3 + 0] = ck0;
  ck_out[t * 3 + 1] = ck1;
  ck_out[t * 3 + 2] = ck2;
  cq_out[t * 3 + 0] = cq0;
  cq_out[t * 3 + 1] = cq1;
  cq_out[t * 3 + 2] = cq2;

  float mean = (cq0 + cq1 + cq2) * (1.f / 3.f);
  float d0 = cq0 - mean, d1 = cq1 - mean, d2 = cq2 - mean;
  float var = (d0 * d0 + d1 * d1 + d2 * d2) * 0.5f;
  float sd  = sqrtf(var);
  float sig = log1pf(__expf(sd));
  float ls  = logf(sig);

  __syncthreads();
  red[tid] = ls;
  __syncthreads();
  for (int r = 128; r > 0; r >>= 1) {
    if (tid < r) red[tid] += red[tid + r];
    __syncthreads();
  }
  if (tid == 0) atomicAdd(loss_acc, red[0]);
}

// ---------------------------------------------------------------------------
// K3: per (bb, lk2): causal 18x18 attention over cluster_q/cluster_k,
// cluster_q2 @ Wb + bias -> relu -> disjoint maxpool(9) -> ccpool.
// ---------------------------------------------------------------------------
__global__ __launch_bounds__(256) void center_kernel(
    const float* __restrict__ cq, const float* __restrict__ ck,
    const float* __restrict__ Wb, const float* __restrict__ bbias,
    float* __restrict__ ccpool) {
  int blk = blockIdx.x;
  int bb  = blk / LK;
  int lk2 = blk % LK;
  int tid = threadIdx.x;

  __shared__ float scq[54], sck[54], sq2[54];
  __shared__ float sWb[3 * 576];
  __shared__ float sbb[576];

  const float* cqb = cq + ((size_t)bb * (LK * B2) + (size_t)lk2 * B2) * 3;
  const float* ckb = ck + ((size_t)bb * (LK * B2) + (size_t)lk2 * B2) * 3;
  if (tid < 54) { scq[tid] = cqb[tid]; sck[tid] = ckb[tid]; }
  for (int i = tid; i < 1728; i += 256) sWb[i] = Wb[i];
  for (int i = tid; i < 576; i += 256) sbb[i] = bbias[i];
  __syncthreads();

  if (tid < B2) {
    int p = tid;
    float s[B2];
    float g0 = scq[p * 3 + 0], g1 = scq[p * 3 + 1], g2 = scq[p * 3 + 2];
    float mx = -INFINITY;
#pragma unroll
    for (int u = 0; u < B2; ++u) {
      float sv = (g0 * sck[u * 3] + g1 * sck[u * 3 + 1] + g2 * sck[u * 3 + 2]) *
                 (1.f / 3.f);
      if (u > p) sv = -1e9f;
      s[u] = sv;
      mx = fmaxf(mx, sv);
    }
    float sum = 0.f;
#pragma unroll
    for (int u = 0; u < B2; ++u) { s[u] = __expf(s[u] - mx); sum += s[u]; }
    float inv = 1.f / sum;
    float o0 = 0.f, o1 = 0.f, o2 = 0.f;
#pragma unroll
    for (int u = 0; u < B2; ++u) {
      float a = s[u] * inv;
      o0 = fmaf(a, scq[u * 3 + 0], o0);
      o1 = fmaf(a, scq[u * 3 + 1], o1);
      o2 = fmaf(a, scq[u * 3 + 2], o2);
    }
    sq2[p * 3 + 0] = o0; sq2[p * 3 + 1] = o1; sq2[p * 3 + 2] = o2;
  }
  __syncthreads();

  float* outb = ccpool + (size_t)bb * CCPOOL_PER_B + (size_t)lk2 * (B2 * 64);
  for (int i = tid; i < B2 * 64; i += 256) {
    int p = i >> 6;
    int w = i & 63;
    float g0 = sq2[p * 3 + 0], g1 = sq2[p * 3 + 1], g2 = sq2[p * 3 + 2];
    int t0 = w * 9 - 4;
    int lo = t0 < 0 ? 0 : t0;
    int hi = t0 + 8; if (hi > 575) hi = 575;
    float mxv = -INFINITY;
    for (int tt = lo; tt <= hi; ++tt) {
      float cv = g0 * sWb[tt] + g1 * sWb[576 + tt] + g2 * sWb[1152 + tt] + sbb[tt];
      cv = fmaxf(cv, 0.f);
      mxv = fmaxf(mxv, cv);
    }
    outb[i] = mxv;
  }
}

// ---------------------------------------------------------------------------
// K4a: prep MFMA operand fragments (hi/lo bf16 split of Csum and Vp).
// ---------------------------------------------------------------------------
#define CFRAG_T (NBH*8*3*64)   // 442368
#define VFRAG_T (NBH*5*4*64)   // 368640
__global__ __launch_bounds__(256) void prep_kernel(
    const float* __restrict__ ccpool, const float* __restrict__ pV,
    uint4* __restrict__ Cfrag, uint4* __restrict__ Vfrag) {
  int t = blockIdx.x * 256 + threadIdx.x;   // 811008 exactly
  unsigned short hi[8], lo[8];
  if (t < CFRAG_T) {
    int lane = t & 63;
    int rest = t >> 6;
    int ks = rest % 3;
    int mtb = rest / 3;
    int mt = mtb & 7;
    int bh = mtb >> 3;
    int bb = bh >> 3, hh = bh & 7;
    int key = mt * 16 + (lane & 15);
    int d0 = ks * 32 + (lane >> 4) * 8;
    const float* cp = ccpool + (size_t)bb * CCPOOL_PER_B + hh * 18432 + key * 72;
#pragma unroll
    for (int j = 0; j < 8; ++j) {
      int d = d0 + j;
      float v = (d < 72) ? (cp[d] + cp[9216 + d]) : 0.f;
      split_hl(v, hi[j], lo[j]);
    }
    uint4 h4, l4;
    h4.x = hi[0] | (hi[1] << 16); h4.y = hi[2] | (hi[3] << 16);
    h4.z = hi[4] | (hi[5] << 16); h4.w = hi[6] | (hi[7] << 16);
    l4.x = lo[0] | (lo[1] << 16); l4.y = lo[2] | (lo[3] << 16);
    l4.z = lo[4] | (lo[5] << 16); l4.w = lo[6] | (lo[7] << 16);
    Cfrag[(size_t)t * 2 + 0] = h4;
    Cfrag[(size_t)t * 2 + 1] = l4;
  } else {
    int t2 = t - CFRAG_T;
    int lane = t2 & 63;
    int rest = t2 >> 6;
    int ks = rest & 3;
    int ntb = rest >> 2;
    int nt = ntb % 5;
    int bh = ntb / 5;
    int d = nt * 16 + (lane & 15);
    int k0 = ks * 32 + (lane >> 4) * 8;
    const float* vp = pV + (size_t)bh * (LK * DK);
#pragma unroll
    for (int j = 0; j < 8; ++j) {
      int k = k0 + j;
      float v = (d < 72) ? vp[k * 72 + d] : 0.f;
      split_hl(v, hi[j], lo[j]);
    }
    uint4 h4, l4;
    h4.x = hi[0] | (hi[1] << 16); h4.y = hi[2] | (hi[3] << 16);
    h4.z = hi[4] | (hi[5] << 16); h4.w = hi[6] | (hi[7] << 16);
    l4.x = lo[0] | (lo[1] << 16); l4.y = lo[2] | (lo[3] << 16);
    l4.z = lo[4] | (lo[5] << 16); l4.w = lo[6] | (lo[7] << 16);
    Vfrag[(size_t)t2 * 2 + 0] = h4;
    Vfrag[(size_t)t2 * 2 + 1] = l4;
  }
}

// ---------------------------------------------------------------------------
// K4b: MFMA attention (unchanged from round 2).
// ---------------------------------------------------------------------------
__global__ __launch_bounds__(256) void attn2_kernel(
    const float* __restrict__ Q, const uint4* __restrict__ Cfrag,
    const uint4* __restrict__ Vfrag, float* __restrict__ out) {
  __shared__ __align__(16) char Plds[4][32 * 272];

  int bh = blockIdx.x / 9, qt = blockIdx.x % 9;
  int wid = threadIdx.x >> 6, lane = threadIdx.x & 63;
  int lq = lane & 15, lg = lane >> 4;
  int qbase = qt * 128 + wid * 32;

  f32x4 sacc[2][8];
#pragma unroll
  for (int s = 0; s < 2; ++s)
#pragma unroll
    for (int mt = 0; mt < 8; ++mt) sacc[s][mt] = (f32x4){0.f, 0.f, 0.f, 0.f};

#pragma unroll
  for (int ks = 0; ks < 3; ++ks) {
    short8 qh[2], ql[2];
#pragma unroll
    for (int s = 0; s < 2; ++s) {
      int q = qbase + s * 16 + lq;
      const float* qrow = Q + ((size_t)bh * L + q) * DK;
      int d0 = ks * 32 + lg * 8;
      float x[8];
      if (ks < 2) {
        float4 a = *(const float4*)(qrow + d0);
        float4 b = *(const float4*)(qrow + d0 + 4);
        x[0] = a.x; x[1] = a.y; x[2] = a.z; x[3] = a.w;
        x[4] = b.x; x[5] = b.y; x[6] = b.z; x[7] = b.w;
      } else {
        if (lg == 0) {
          float4 a = *(const float4*)(qrow + 64);
          float4 b = *(const float4*)(qrow + 68);
          x[0] = a.x; x[1] = a.y; x[2] = a.z; x[3] = a.w;
          x[4] = b.x; x[5] = b.y; x[6] = b.z; x[7] = b.w;
        } else {
#pragma unroll
          for (int j = 0; j < 8; ++j) x[j] = 0.f;
        }
      }
#pragma unroll
      for (int j = 0; j < 8; ++j) {
        unsigned short h, l2;
        split_hl(x[j], h, l2);
        qh[s][j] = (short)h;
        ql[s][j] = (short)l2;
      }
    }
#pragma unroll
    for (int mt = 0; mt < 8; ++mt) {
      const short8* cp8 = (const short8*)(Cfrag +
          ((((size_t)bh * 8 + mt) * 3 + ks) * 64 + lane) * 2);
      short8 chi = cp8[0];
      short8 clo = cp8[1];
#pragma unroll
      for (int s = 0; s < 2; ++s) {
        sacc[s][mt] = __builtin_amdgcn_mfma_f32_16x16x32_bf16(chi, qh[s], sacc[s][mt], 0, 0, 0);
        sacc[s][mt] = __builtin_amdgcn_mfma_f32_16x16x32_bf16(chi, ql[s], sacc[s][mt], 0, 0, 0);
        sacc[s][mt] = __builtin_amdgcn_mfma_f32_16x16x32_bf16(clo, qh[s], sacc[s][mt], 0, 0, 0);
      }
    }
  }

  char* pb = Plds[wid];
#pragma unroll
  for (int s = 0; s < 2; ++s) {
    float mx = -INFINITY;
#pragma unroll
    for (int mt = 0; mt < 8; ++mt)
#pragma unroll
      for (int r = 0; r < 4; ++r) mx = fmaxf(mx, sacc[s][mt][r]);
    mx = fmaxf(mx, __shfl_xor(mx, 16));
    mx = fmaxf(mx, __shfl_xor(mx, 32));
    float sum = 0.f;
#pragma unroll
    for (int mt = 0; mt < 8; ++mt)
#pragma unroll
      for (int r = 0; r < 4; ++r) {
        float p = __expf(sacc[s][mt][r] - mx);
        sacc[s][mt][r] = p;
        sum += p;
      }
    sum += __shfl_xor(sum, 16);
    sum += __shfl_xor(sum, 32);
    float inv = 1.f / sum;
    int row = s * 16 + lq;
    unsigned roff = row * 272;
    unsigned sw = (unsigned)((row & 7) << 4);
#pragma unroll
    for (int mt = 0; mt < 8; ++mt) {
      unsigned w0 = pack2(sacc[s][mt][0] * inv, sacc[s][mt][1] * inv);
      unsigned w1 = pack2(sacc[s][mt][2] * inv, sacc[s][mt][3] * inv);
      unsigned off = (roff + mt * 32 + lg * 8) ^ sw;
      *(uint2*)(pb + off) = make_uint2(w0, w1);
    }
  }

  f32x4 oacc[2][5];
#pragma unroll
  for (int s = 0; s < 2; ++s)
#pragma unroll
    for (int nt = 0; nt < 5; ++nt) oacc[s][nt] = (f32x4){0.f, 0.f, 0.f, 0.f};

#pragma unroll
  for (int ks = 0; ks < 4; ++ks) {
    short8 pa[2];
#pragma unroll
    for (int s = 0; s < 2; ++s) {
      int row = s * 16 + lq;
      unsigned off = ((unsigned)row * 272 + ks * 64 + lg * 16) ^
                     (unsigned)((row & 7) << 4);
      pa[s] = *(const short8*)(pb + off);
    }
#pragma unroll
    for (int nt = 0; nt < 5; ++nt) {
      const short8* vp8 = (const short8*)(Vfrag +
          ((((size_t)bh * 5 + nt) * 4 + ks) * 64 + lane) * 2);
      short8 vhi = vp8[0];
      short8 vlo = vp8[1];
#pragma unroll
      for (int s = 0; s < 2; ++s) {
        oacc[s][nt] = __builtin_amdgcn_mfma_f32_16x16x32_bf16(pa[s], vhi, oacc[s][nt], 0, 0, 0);
        oacc[s][nt] = __builtin_amdgcn_mfma_f32_16x16x32_bf16(pa[s], vlo, oacc[s][nt], 0, 0, 0);
      }
    }
  }

#pragma unroll
  for (int s = 0; s < 2; ++s) {
#pragma unroll
    for (int nt = 0; nt < 5; ++nt) {
      int d = nt * 16 + lq;
      if (d < 72) {
        float* orow = out + ((size_t)bh * L + qbase + s * 16 + lg * 4) * DK + d;
#pragma unroll
        for (int r = 0; r < 4; ++r) orow[(size_t)r * DK] = oacc[s][nt][r];
      }
    }
  }
}

// ---------------------------------------------------------------------------
// K5: finalize loss (mu == xk == 1/3 exactly; ce is a constant).
// ---------------------------------------------------------------------------
__global__ void finalize_kernel(const float* __restrict__ loss_acc,
                                float* __restrict__ out_loss) {
  *out_loss = loss_acc[0] * (1.f / 82944.f) + 207.93889646f;
}

extern "C" void kernel_launch(void* const* d_in, const int* in_sizes, int n_in,
                              void* d_out, int out_size, void* d_ws, size_t ws_size,
                              hipStream_t stream) {
  const float* Q    = (const float*)d_in[0];
  const float* Kin  = (const float*)d_in[1];
  const float* Vin  = (const float*)d_in[2];
  const float* Wp   = (const float*)d_in[3];
  const float* bp   = (const float*)d_in[4];
  const float* Wck  = (const float*)d_in[5];
  const float* bck  = (const float*)d_in[6];
  const float* Wcq  = (const float*)d_in[7];
  const float* bcq  = (const float*)d_in[8];
  const float* Wb   = (const float*)d_in[9];
  const float* bbv  = (const float*)d_in[10];
  float* out = (float*)d_out;

  float* ws = (float*)d_ws;
  float* pK       = ws;
  float* pV       = pK + POOL_TOTAL;
  float* cq       = pV + POOL_TOTAL;
  float* ck       = cq + (size_t)CLUS_TOTAL * 3;
  float* ccpool   = ck + (size_t)CLUS_TOTAL * 3;
  float* cfrag_f  = ccpool + (size_t)BATCH * CCPOOL_PER_B;
  uint4* Cfrag    = (uint4*)cfrag_f;
  uint4* Vfrag    = Cfrag + (size_t)CFRAG_T * 2;
  float* loss_acc = (float*)(Vfrag + (size_t)VFRAG_T * 2);

  hipMemsetAsync(loss_acc, 0, sizeof(float), stream);

  pool_kernel<<<POOL_TOTAL / 256, 256, 0, stream>>>(Kin, Vin, pK, pV);
  cluster_kernel<<<BATCH * 9, 256, 0, stream>>>(
      pK, Wp, bp, Wck, bck, Wcq, bcq, cq, ck, loss_acc);
  center_kernel<<<BATCH * LK, 256, 0, stream>>>(cq, ck, Wb, bbv, ccpool);
  prep_kernel<<<(CFRAG_T + VFRAG_T) / 256, 256, 0, stream>>>(ccpool, pV, Cfrag, Vfrag);
  attn2_kernel<<<NBH * 9, 256, 0, stream>>>(Q, Cfrag, Vfrag, out);
  finalize_kernel<<<1, 1, 0, stream>>>(loss_acc, out + CTX_ELEMS);
}

// Round 4
// 229.041 us; speedup vs baseline: 4.5625x; 1.1599x over previous
//
#include <hip/hip_runtime.h>
#include <math.h>

#define BATCH 36
#define H 8
#define L 1152
#define DK 72
#define DM 576
#define LK 128
#define B2 18
#define NC 3

// derived
#define POOL_PER_B (DM*LK)            // 73728
#define POOL_TOTAL (BATCH*POOL_PER_B) // 2654208
#define CLUS_TOTAL (BATCH*LK*B2)      // 82944
#define CCPOOL_PER_B (LK*B2*64)       // 147456
#define CTX_ELEMS (BATCH*H*L*DK)      // 23887872
#define NBH (BATCH*H)                 // 288

typedef __attribute__((ext_vector_type(8))) short short8;
typedef __attribute__((ext_vector_type(4))) float f32x4;

// round-to-nearest-even fp32 -> bf16 bits
__device__ __forceinline__ unsigned short bf16_rne(float x) {
  unsigned u = __float_as_uint(x);
  unsigned r = u + 0x7FFFu + ((u >> 16) & 1u);
  return (unsigned short)(r >> 16);
}
__device__ __forceinline__ void split_hl(float x, unsigned short& h, unsigned short& l) {
  h = bf16_rne(x);
  float fh = __uint_as_float(((unsigned)h) << 16);
  l = bf16_rne(x - fh);
}
__device__ __forceinline__ unsigned pack2(float a, float b) {
  return (unsigned)bf16_rne(a) | ((unsigned)bf16_rne(b) << 16);
}

// ---------------------------------------------------------------------------
// K1: MaxPool1d(kernel=9, stride=9, pad=4) on K,V viewed as (20736 rows x
// 1152). Windows are DISJOINT (stride==kernel), so this is a segmented max.
// Block: 8 contiguous rows staged via coalesced float4 -> LDS; each thread
// reduces 9-elem segments from LDS (stride-9 = 2-way bank alias, free) and
// writes a contiguous output block. w=0 negative indices clamp to 0 (dup
// values are harmless under max).
// ---------------------------------------------------------------------------
#define PROWS 8
__global__ __launch_bounds__(256) void pool_kernel(
    const float* __restrict__ Kin, const float* __restrict__ Vin,
    float* __restrict__ pK, float* __restrict__ pV) {
  __shared__ float sIn[PROWS * L];    // 36 KB

  int bid = blockIdx.x;
  const int half = (BATCH * DM) / PROWS;   // 2592
  const float* src;
  float* dst;
  if (bid < half) {
    src = Kin + (size_t)bid * (PROWS * L);
    dst = pK + (size_t)bid * (PROWS * LK);
  } else {
    src = Vin + (size_t)(bid - half) * (PROWS * L);
    dst = pV + (size_t)(bid - half) * (PROWS * LK);
  }
  int tid = threadIdx.x;

  const float4* s4 = (const float4*)src;
  float4* l4 = (float4*)sIn;
#pragma unroll
  for (int k = 0; k < (PROWS * L) / 4 / 256; ++k)   // 9 iters
    l4[tid + k * 256] = s4[tid + k * 256];
  __syncthreads();

#pragma unroll
  for (int k = 0; k < (PROWS * LK) / 256; ++k) {    // 4 iters
    int o = tid + k * 256;
    int row = o >> 7, w = o & 127;
    int base = row * L;
    int s0 = w * 9 - 4;                // >= -4; hi = w*9+4 <= 1147 < L always
    float m = -INFINITY;
#pragma unroll
    for (int j = 0; j < 9; ++j) {
      int t = s0 + j;
      t = t < 0 ? 0 : t;
      m = fmaxf(m, sIn[base + t]);
    }
    dst[o] = m;
  }
}

// ---------------------------------------------------------------------------
// K2: clustering head (identity-gather form; see round-2 notes).
// ---------------------------------------------------------------------------
__global__ __launch_bounds__(256) void cluster_kernel(
    const float* __restrict__ pK,
    const float* __restrict__ Wp,  const float* __restrict__ bp,
    const float* __restrict__ Wck, const float* __restrict__ bck,
    const float* __restrict__ Wcq, const float* __restrict__ bcq,
    float* __restrict__ cq_out, float* __restrict__ ck_out,
    float* __restrict__ loss_acc) {
  int bb = blockIdx.x / 9;
  int s  = blockIdx.x % 9;
  int tid = threadIdx.x;

  __shared__ float sK[256 * 33];
  __shared__ float sWp[1728];
  __shared__ float red[256];

  for (int i = tid; i < 1728; i += 256) sWp[i] = Wp[i];

  float a0 = 0.f, a1 = 0.f, a2 = 0.f;
  int umin = (bb >= 18) ? 0 : (18 - bb);

  for (int u = umin; u < 18; ++u) {
    int b2 = bb + u - 17;
    __syncthreads();
    const float4* src = (const float4*)(pK + (size_t)b2 * POOL_PER_B + s * 8192);
#pragma unroll
    for (int k = 0; k < 8; ++k) {
      int i = tid + k * 256;
      float4 v = src[i];
      int base = i * 4;
      float* dst = &sK[(base >> 5) * 33 + (base & 31)];
      dst[0] = v.x; dst[1] = v.y; dst[2] = v.z; dst[3] = v.w;
    }
    __syncthreads();
    const float* wrow = &sWp[u * 3];
    const float* krow = &sK[tid * 33];
#pragma unroll
    for (int g = 0; g < 32; ++g) {
      float v = krow[g];
      a0 = fmaf(v, wrow[g * 54 + 0], a0);
      a1 = fmaf(v, wrow[g * 54 + 1], a1);
      a2 = fmaf(v, wrow[g * 54 + 2], a2);
    }
  }

  float p0 = fmaxf(a0 + bp[0], 0.f);
  float p1 = fmaxf(a1 + bp[1], 0.f);
  float p2 = fmaxf(a2 + bp[2], 0.f);

  float k0 = p0 * Wck[0] + p1 * Wck[3] + p2 * Wck[6] + bck[0];
  float k1 = p0 * Wck[1] + p1 * Wck[4] + p2 * Wck[7] + bck[1];
  float k2 = p0 * Wck[2] + p1 * Wck[5] + p2 * Wck[8] + bck[2];
  float mk = fmaxf(k0, fmaxf(k1, k2));
  float e0 = __expf(k0 - mk), e1 = __expf(k1 - mk), e2 = __expf(k2 - mk);
  float inv = 1.f / (e0 + e1 + e2);
  float ck0 = e0 * inv, ck1 = e1 * inv, ck2 = e2 * inv;

  float q0 = p0 * Wcq[0] + p1 * Wcq[3] + p2 * Wcq[6] + bcq[0];
  float q1 = p0 * Wcq[1] + p1 * Wcq[4] + p2 * Wcq[7] + bcq[1];
  float q2 = p0 * Wcq[2] + p1 * Wcq[5] + p2 * Wcq[8] + bcq[2];
  float mq = fmaxf(q0, fmaxf(q1, q2));
  float f0 = __expf(q0 - mq), f1 = __expf(q1 - mq), f2 = __expf(q2 - mq);
  float invq = 1.f / (f0 + f1 + f2);
  float cq0 = f0 * invq, cq1 = f1 * invq, cq2 = f2 * invq;

  size_t t = (size_t)bb * 2304 + s * 256 + tid;
  ck_out[t * 3 + 0] = ck0;
  ck_out[t * 3 + 1] = ck1;
  ck_out[t * 3 + 2] = ck2;
  cq_out[t * 3 + 0] = cq0;
  cq_out[t * 3 + 1] = cq1;
  cq_out[t * 3 + 2] = cq2;

  float mean = (cq0 + cq1 + cq2) * (1.f / 3.f);
  float d0 = cq0 - mean, d1 = cq1 - mean, d2 = cq2 - mean;
  float var = (d0 * d0 + d1 * d1 + d2 * d2) * 0.5f;
  float sd  = sqrtf(var);
  float sig = log1pf(__expf(sd));
  float ls  = logf(sig);

  __syncthreads();
  red[tid] = ls;
  __syncthreads();
  for (int r = 128; r > 0; r >>= 1) {
    if (tid < r) red[tid] += red[tid + r];
    __syncthreads();
  }
  if (tid == 0) atomicAdd(loss_acc, red[0]);
}

// ---------------------------------------------------------------------------
// K3: per (bb, lk2): causal 18x18 attention over cluster_q/cluster_k,
// cluster_q2 @ Wb + bias -> relu -> disjoint maxpool(9) -> ccpool.
// ---------------------------------------------------------------------------
__global__ __launch_bounds__(256) void center_kernel(
    const float* __restrict__ cq, const float* __restrict__ ck,
    const float* __restrict__ Wb, const float* __restrict__ bbias,
    float* __restrict__ ccpool) {
  int blk = blockIdx.x;
  int bb  = blk / LK;
  int lk2 = blk % LK;
  int tid = threadIdx.x;

  __shared__ float scq[54], sck[54], sq2[54];
  __shared__ float sWb[3 * 576];
  __shared__ float sbb[576];

  const float* cqb = cq + ((size_t)bb * (LK * B2) + (size_t)lk2 * B2) * 3;
  const float* ckb = ck + ((size_t)bb * (LK * B2) + (size_t)lk2 * B2) * 3;
  if (tid < 54) { scq[tid] = cqb[tid]; sck[tid] = ckb[tid]; }
  for (int i = tid; i < 1728; i += 256) sWb[i] = Wb[i];
  for (int i = tid; i < 576; i += 256) sbb[i] = bbias[i];
  __syncthreads();

  if (tid < B2) {
    int p = tid;
    float s[B2];
    float g0 = scq[p * 3 + 0], g1 = scq[p * 3 + 1], g2 = scq[p * 3 + 2];
    float mx = -INFINITY;
#pragma unroll
    for (int u = 0; u < B2; ++u) {
      float sv = (g0 * sck[u * 3] + g1 * sck[u * 3 + 1] + g2 * sck[u * 3 + 2]) *
                 (1.f / 3.f);
      if (u > p) sv = -1e9f;
      s[u] = sv;
      mx = fmaxf(mx, sv);
    }
    float sum = 0.f;
#pragma unroll
    for (int u = 0; u < B2; ++u) { s[u] = __expf(s[u] - mx); sum += s[u]; }
    float inv = 1.f / sum;
    float o0 = 0.f, o1 = 0.f, o2 = 0.f;
#pragma unroll
    for (int u = 0; u < B2; ++u) {
      float a = s[u] * inv;
      o0 = fmaf(a, scq[u * 3 + 0], o0);
      o1 = fmaf(a, scq[u * 3 + 1], o1);
      o2 = fmaf(a, scq[u * 3 + 2], o2);
    }
    sq2[p * 3 + 0] = o0; sq2[p * 3 + 1] = o1; sq2[p * 3 + 2] = o2;
  }
  __syncthreads();

  float* outb = ccpool + (size_t)bb * CCPOOL_PER_B + (size_t)lk2 * (B2 * 64);
  for (int i = tid; i < B2 * 64; i += 256) {
    int p = i >> 6;
    int w = i & 63;
    float g0 = sq2[p * 3 + 0], g1 = sq2[p * 3 + 1], g2 = sq2[p * 3 + 2];
    int t0 = w * 9 - 4;
    int lo = t0 < 0 ? 0 : t0;
    int hi = t0 + 8; if (hi > 575) hi = 575;
    float mxv = -INFINITY;
    for (int tt = lo; tt <= hi; ++tt) {
      float cv = g0 * sWb[tt] + g1 * sWb[576 + tt] + g2 * sWb[1152 + tt] + sbb[tt];
      cv = fmaxf(cv, 0.f);
      mxv = fmaxf(mxv, cv);
    }
    outb[i] = mxv;
  }
}

// ---------------------------------------------------------------------------
// K4a: prep MFMA operand fragments (hi/lo bf16 split of Csum and Vp).
// ---------------------------------------------------------------------------
#define CFRAG_T (NBH*8*3*64)   // 442368
#define VFRAG_T (NBH*5*4*64)   // 368640
__global__ __launch_bounds__(256) void prep_kernel(
    const float* __restrict__ ccpool, const float* __restrict__ pV,
    uint4* __restrict__ Cfrag, uint4* __restrict__ Vfrag) {
  int t = blockIdx.x * 256 + threadIdx.x;   // 811008 exactly
  unsigned short hi[8], lo[8];
  if (t < CFRAG_T) {
    int lane = t & 63;
    int rest = t >> 6;
    int ks = rest % 3;
    int mtb = rest / 3;
    int mt = mtb & 7;
    int bh = mtb >> 3;
    int bb = bh >> 3, hh = bh & 7;
    int key = mt * 16 + (lane & 15);
    int d0 = ks * 32 + (lane >> 4) * 8;
    const float* cp = ccpool + (size_t)bb * CCPOOL_PER_B + hh * 18432 + key * 72;
#pragma unroll
    for (int j = 0; j < 8; ++j) {
      int d = d0 + j;
      float v = (d < 72) ? (cp[d] + cp[9216 + d]) : 0.f;
      split_hl(v, hi[j], lo[j]);
    }
    uint4 h4, l4;
    h4.x = hi[0] | (hi[1] << 16); h4.y = hi[2] | (hi[3] << 16);
    h4.z = hi[4] | (hi[5] << 16); h4.w = hi[6] | (hi[7] << 16);
    l4.x = lo[0] | (lo[1] << 16); l4.y = lo[2] | (lo[3] << 16);
    l4.z = lo[4] | (lo[5] << 16); l4.w = lo[6] | (lo[7] << 16);
    Cfrag[(size_t)t * 2 + 0] = h4;
    Cfrag[(size_t)t * 2 + 1] = l4;
  } else {
    int t2 = t - CFRAG_T;
    int lane = t2 & 63;
    int rest = t2 >> 6;
    int ks = rest & 3;
    int ntb = rest >> 2;
    int nt = ntb % 5;
    int bh = ntb / 5;
    int d = nt * 16 + (lane & 15);
    int k0 = ks * 32 + (lane >> 4) * 8;
    const float* vp = pV + (size_t)bh * (LK * DK);
#pragma unroll
    for (int j = 0; j < 8; ++j) {
      int k = k0 + j;
      float v = (d < 72) ? vp[k * 72 + d] : 0.f;
      split_hl(v, hi[j], lo[j]);
    }
    uint4 h4, l4;
    h4.x = hi[0] | (hi[1] << 16); h4.y = hi[2] | (hi[3] << 16);
    h4.z = hi[4] | (hi[5] << 16); h4.w = hi[6] | (hi[7] << 16);
    l4.x = lo[0] | (lo[1] << 16); l4.y = lo[2] | (lo[3] << 16);
    l4.z = lo[4] | (lo[5] << 16); l4.w = lo[6] | (lo[7] << 16);
    Vfrag[(size_t)t2 * 2 + 0] = h4;
    Vfrag[(size_t)t2 * 2 + 1] = l4;
  }
}

// ---------------------------------------------------------------------------
// K4b: MFMA attention.
// ---------------------------------------------------------------------------
__global__ __launch_bounds__(256) void attn2_kernel(
    const float* __restrict__ Q, const uint4* __restrict__ Cfrag,
    const uint4* __restrict__ Vfrag, float* __restrict__ out) {
  __shared__ __align__(16) char Plds[4][32 * 272];

  int bh = blockIdx.x / 9, qt = blockIdx.x % 9;
  int wid = threadIdx.x >> 6, lane = threadIdx.x & 63;
  int lq = lane & 15, lg = lane >> 4;
  int qbase = qt * 128 + wid * 32;

  f32x4 sacc[2][8];
#pragma unroll
  for (int s = 0; s < 2; ++s)
#pragma unroll
    for (int mt = 0; mt < 8; ++mt) sacc[s][mt] = (f32x4){0.f, 0.f, 0.f, 0.f};

#pragma unroll
  for (int ks = 0; ks < 3; ++ks) {
    short8 qh[2], ql[2];
#pragma unroll
    for (int s = 0; s < 2; ++s) {
      int q = qbase + s * 16 + lq;
      const float* qrow = Q + ((size_t)bh * L + q) * DK;
      int d0 = ks * 32 + lg * 8;
      float x[8];
      if (ks < 2) {
        float4 a = *(const float4*)(qrow + d0);
        float4 b = *(const float4*)(qrow + d0 + 4);
        x[0] = a.x; x[1] = a.y; x[2] = a.z; x[3] = a.w;
        x[4] = b.x; x[5] = b.y; x[6] = b.z; x[7] = b.w;
      } else {
        if (lg == 0) {
          float4 a = *(const float4*)(qrow + 64);
          float4 b = *(const float4*)(qrow + 68);
          x[0] = a.x; x[1] = a.y; x[2] = a.z; x[3] = a.w;
          x[4] = b.x; x[5] = b.y; x[6] = b.z; x[7] = b.w;
        } else {
#pragma unroll
          for (int j = 0; j < 8; ++j) x[j] = 0.f;
        }
      }
#pragma unroll
      for (int j = 0; j < 8; ++j) {
        unsigned short h, l2;
        split_hl(x[j], h, l2);
        qh[s][j] = (short)h;
        ql[s][j] = (short)l2;
      }
    }
#pragma unroll
    for (int mt = 0; mt < 8; ++mt) {
      const short8* cp8 = (const short8*)(Cfrag +
          ((((size_t)bh * 8 + mt) * 3 + ks) * 64 + lane) * 2);
      short8 chi = cp8[0];
      short8 clo = cp8[1];
#pragma unroll
      for (int s = 0; s < 2; ++s) {
        sacc[s][mt] = __builtin_amdgcn_mfma_f32_16x16x32_bf16(chi, qh[s], sacc[s][mt], 0, 0, 0);
        sacc[s][mt] = __builtin_amdgcn_mfma_f32_16x16x32_bf16(chi, ql[s], sacc[s][mt], 0, 0, 0);
        sacc[s][mt] = __builtin_amdgcn_mfma_f32_16x16x32_bf16(clo, qh[s], sacc[s][mt], 0, 0, 0);
      }
    }
  }

  char* pb = Plds[wid];
#pragma unroll
  for (int s = 0; s < 2; ++s) {
    float mx = -INFINITY;
#pragma unroll
    for (int mt = 0; mt < 8; ++mt)
#pragma unroll
      for (int r = 0; r < 4; ++r) mx = fmaxf(mx, sacc[s][mt][r]);
    mx = fmaxf(mx, __shfl_xor(mx, 16));
    mx = fmaxf(mx, __shfl_xor(mx, 32));
    float sum = 0.f;
#pragma unroll
    for (int mt = 0; mt < 8; ++mt)
#pragma unroll
      for (int r = 0; r < 4; ++r) {
        float p = __expf(sacc[s][mt][r] - mx);
        sacc[s][mt][r] = p;
        sum += p;
      }
    sum += __shfl_xor(sum, 16);
    sum += __shfl_xor(sum, 32);
    float inv = 1.f / sum;
    int row = s * 16 + lq;
    unsigned roff = row * 272;
    unsigned sw = (unsigned)((row & 7) << 4);
#pragma unroll
    for (int mt = 0; mt < 8; ++mt) {
      unsigned w0 = pack2(sacc[s][mt][0] * inv, sacc[s][mt][1] * inv);
      unsigned w1 = pack2(sacc[s][mt][2] * inv, sacc[s][mt][3] * inv);
      unsigned off = (roff + mt * 32 + lg * 8) ^ sw;
      *(uint2*)(pb + off) = make_uint2(w0, w1);
    }
  }

  f32x4 oacc[2][5];
#pragma unroll
  for (int s = 0; s < 2; ++s)
#pragma unroll
    for (int nt = 0; nt < 5; ++nt) oacc[s][nt] = (f32x4){0.f, 0.f, 0.f, 0.f};

#pragma unroll
  for (int ks = 0; ks < 4; ++ks) {
    short8 pa[2];
#pragma unroll
    for (int s = 0; s < 2; ++s) {
      int row = s * 16 + lq;
      unsigned off = ((unsigned)row * 272 + ks * 64 + lg * 16) ^
                     (unsigned)((row & 7) << 4);
      pa[s] = *(const short8*)(pb + off);
    }
#pragma unroll
    for (int nt = 0; nt < 5; ++nt) {
      const short8* vp8 = (const short8*)(Vfrag +
          ((((size_t)bh * 5 + nt) * 4 + ks) * 64 + lane) * 2);
      short8 vhi = vp8[0];
      short8 vlo = vp8[1];
#pragma unroll
      for (int s = 0; s < 2; ++s) {
        oacc[s][nt] = __builtin_amdgcn_mfma_f32_16x16x32_bf16(pa[s], vhi, oacc[s][nt], 0, 0, 0);
        oacc[s][nt] = __builtin_amdgcn_mfma_f32_16x16x32_bf16(pa[s], vlo, oacc[s][nt], 0, 0, 0);
      }
    }
  }

#pragma unroll
  for (int s = 0; s < 2; ++s) {
#pragma unroll
    for (int nt = 0; nt < 5; ++nt) {
      int d = nt * 16 + lq;
      if (d < 72) {
        float* orow = out + ((size_t)bh * L + qbase + s * 16 + lg * 4) * DK + d;
#pragma unroll
        for (int r = 0; r < 4; ++r) orow[(size_t)r * DK] = oacc[s][nt][r];
      }
    }
  }
}

// ---------------------------------------------------------------------------
// K5: finalize loss (mu == xk == 1/3 exactly; ce is a constant).
// ---------------------------------------------------------------------------
__global__ void finalize_kernel(const float* __restrict__ loss_acc,
                                float* __restrict__ out_loss) {
  *out_loss = loss_acc[0] * (1.f / 82944.f) + 207.93889646f;
}

extern "C" void kernel_launch(void* const* d_in, const int* in_sizes, int n_in,
                              void* d_out, int out_size, void* d_ws, size_t ws_size,
                              hipStream_t stream) {
  const float* Q    = (const float*)d_in[0];
  const float* Kin  = (const float*)d_in[1];
  const float* Vin  = (const float*)d_in[2];
  const float* Wp   = (const float*)d_in[3];
  const float* bp   = (const float*)d_in[4];
  const float* Wck  = (const float*)d_in[5];
  const float* bck  = (const float*)d_in[6];
  const float* Wcq  = (const float*)d_in[7];
  const float* bcq  = (const float*)d_in[8];
  const float* Wb   = (const float*)d_in[9];
  const float* bbv  = (const float*)d_in[10];
  float* out = (float*)d_out;

  float* ws = (float*)d_ws;
  float* pK       = ws;
  float* pV       = pK + POOL_TOTAL;
  float* cq       = pV + POOL_TOTAL;
  float* ck       = cq + (size_t)CLUS_TOTAL * 3;
  float* ccpool   = ck + (size_t)CLUS_TOTAL * 3;
  float* cfrag_f  = ccpool + (size_t)BATCH * CCPOOL_PER_B;
  uint4* Cfrag    = (uint4*)cfrag_f;
  uint4* Vfrag    = Cfrag + (size_t)CFRAG_T * 2;
  float* loss_acc = (float*)(Vfrag + (size_t)VFRAG_T * 2);

  hipMemsetAsync(loss_acc, 0, sizeof(float), stream);

  pool_kernel<<<2 * (BATCH * DM) / PROWS, 256, 0, stream>>>(Kin, Vin, pK, pV);
  cluster_kernel<<<BATCH * 9, 256, 0, stream>>>(
      pK, Wp, bp, Wck, bck, Wcq, bcq, cq, ck, loss_acc);
  center_kernel<<<BATCH * LK, 256, 0, stream>>>(cq, ck, Wb, bbv, ccpool);
  prep_kernel<<<(CFRAG_T + VFRAG_T) / 256, 256, 0, stream>>>(ccpool, pV, Cfrag, Vfrag);
  attn2_kernel<<<NBH * 9, 256, 0, stream>>>(Q, Cfrag, Vfrag, out);
  finalize_kernel<<<1, 1, 0, stream>>>(loss_acc, out + CTX_ELEMS);
}

// Round 5
// 203.192 us; speedup vs baseline: 5.1429x; 1.1272x over previous
//
#include <hip/hip_runtime.h>
#include <math.h>

#define BATCH 36
#define H 8
#define L 1152
#define DK 72
#define DM 576
#define LK 128
#define B2 18
#define NC 3

// derived
#define POOL_PER_B (DM*LK)            // 73728
#define POOL_TOTAL (BATCH*POOL_PER_B) // 2654208
#define CLUS_TOTAL (BATCH*LK*B2)      // 82944
#define CCPOOL_PER_B (LK*B2*64)       // 147456
#define CTX_ELEMS (BATCH*H*L*DK)      // 23887872
#define NBH (BATCH*H)                 // 288

typedef __attribute__((ext_vector_type(8))) short short8;
typedef __attribute__((ext_vector_type(4))) float f32x4;

// round-to-nearest-even fp32 -> bf16 bits
__device__ __forceinline__ unsigned short bf16_rne(float x) {
  unsigned u = __float_as_uint(x);
  unsigned r = u + 0x7FFFu + ((u >> 16) & 1u);
  return (unsigned short)(r >> 16);
}
__device__ __forceinline__ void split_hl(float x, unsigned short& h, unsigned short& l) {
  h = bf16_rne(x);
  float fh = __uint_as_float(((unsigned)h) << 16);
  l = bf16_rne(x - fh);
}
__device__ __forceinline__ unsigned pack2(float a, float b) {
  return (unsigned)bf16_rne(a) | ((unsigned)bf16_rne(b) << 16);
}

// ---------------------------------------------------------------------------
// K1: MaxPool1d(kernel=9, stride=9, pad=4), disjoint-window segmented max.
// ---------------------------------------------------------------------------
#define PROWS 8
__global__ __launch_bounds__(256) void pool_kernel(
    const float* __restrict__ Kin, const float* __restrict__ Vin,
    float* __restrict__ pK, float* __restrict__ pV) {
  __shared__ float sIn[PROWS * L];    // 36 KB

  int bid = blockIdx.x;
  const int half = (BATCH * DM) / PROWS;   // 2592
  const float* src;
  float* dst;
  if (bid < half) {
    src = Kin + (size_t)bid * (PROWS * L);
    dst = pK + (size_t)bid * (PROWS * LK);
  } else {
    src = Vin + (size_t)(bid - half) * (PROWS * L);
    dst = pV + (size_t)(bid - half) * (PROWS * LK);
  }
  int tid = threadIdx.x;

  const float4* s4 = (const float4*)src;
  float4* l4 = (float4*)sIn;
#pragma unroll
  for (int k = 0; k < (PROWS * L) / 4 / 256; ++k)   // 9 iters
    l4[tid + k * 256] = s4[tid + k * 256];
  __syncthreads();

#pragma unroll
  for (int k = 0; k < (PROWS * LK) / 256; ++k) {    // 4 iters
    int o = tid + k * 256;
    int row = o >> 7, w = o & 127;
    int base = row * L;
    int s0 = w * 9 - 4;
    float m = -INFINITY;
#pragma unroll
    for (int j = 0; j < 9; ++j) {
      int t = s0 + j;
      t = t < 0 ? 0 : t;
      m = fmaxf(m, sIn[base + t]);
    }
    dst[o] = m;
  }
}

// ---------------------------------------------------------------------------
// K2: clustering head (identity-gather form).
// ---------------------------------------------------------------------------
__global__ __launch_bounds__(256) void cluster_kernel(
    const float* __restrict__ pK,
    const float* __restrict__ Wp,  const float* __restrict__ bp,
    const float* __restrict__ Wck, const float* __restrict__ bck,
    const float* __restrict__ Wcq, const float* __restrict__ bcq,
    float* __restrict__ cq_out, float* __restrict__ ck_out,
    float* __restrict__ loss_acc) {
  int bb = blockIdx.x / 9;
  int s  = blockIdx.x % 9;
  int tid = threadIdx.x;

  __shared__ float sK[256 * 33];
  __shared__ float sWp[1728];
  __shared__ float red[256];

  for (int i = tid; i < 1728; i += 256) sWp[i] = Wp[i];

  float a0 = 0.f, a1 = 0.f, a2 = 0.f;
  int umin = (bb >= 18) ? 0 : (18 - bb);

  for (int u = umin; u < 18; ++u) {
    int b2 = bb + u - 17;
    __syncthreads();
    const float4* src = (const float4*)(pK + (size_t)b2 * POOL_PER_B + s * 8192);
#pragma unroll
    for (int k = 0; k < 8; ++k) {
      int i = tid + k * 256;
      float4 v = src[i];
      int base = i * 4;
      float* dst = &sK[(base >> 5) * 33 + (base & 31)];
      dst[0] = v.x; dst[1] = v.y; dst[2] = v.z; dst[3] = v.w;
    }
    __syncthreads();
    const float* wrow = &sWp[u * 3];
    const float* krow = &sK[tid * 33];
#pragma unroll
    for (int g = 0; g < 32; ++g) {
      float v = krow[g];
      a0 = fmaf(v, wrow[g * 54 + 0], a0);
      a1 = fmaf(v, wrow[g * 54 + 1], a1);
      a2 = fmaf(v, wrow[g * 54 + 2], a2);
    }
  }

  float p0 = fmaxf(a0 + bp[0], 0.f);
  float p1 = fmaxf(a1 + bp[1], 0.f);
  float p2 = fmaxf(a2 + bp[2], 0.f);

  float k0 = p0 * Wck[0] + p1 * Wck[3] + p2 * Wck[6] + bck[0];
  float k1 = p0 * Wck[1] + p1 * Wck[4] + p2 * Wck[7] + bck[1];
  float k2 = p0 * Wck[2] + p1 * Wck[5] + p2 * Wck[8] + bck[2];
  float mk = fmaxf(k0, fmaxf(k1, k2));
  float e0 = __expf(k0 - mk), e1 = __expf(k1 - mk), e2 = __expf(k2 - mk);
  float inv = 1.f / (e0 + e1 + e2);
  float ck0 = e0 * inv, ck1 = e1 * inv, ck2 = e2 * inv;

  float q0 = p0 * Wcq[0] + p1 * Wcq[3] + p2 * Wcq[6] + bcq[0];
  float q1 = p0 * Wcq[1] + p1 * Wcq[4] + p2 * Wcq[7] + bcq[1];
  float q2 = p0 * Wcq[2] + p1 * Wcq[5] + p2 * Wcq[8] + bcq[2];
  float mq = fmaxf(q0, fmaxf(q1, q2));
  float f0 = __expf(q0 - mq), f1 = __expf(q1 - mq), f2 = __expf(q2 - mq);
  float invq = 1.f / (f0 + f1 + f2);
  float cq0 = f0 * invq, cq1 = f1 * invq, cq2 = f2 * invq;

  size_t t = (size_t)bb * 2304 + s * 256 + tid;
  ck_out[t * 3 + 0] = ck0;
  ck_out[t * 3 + 1] = ck1;
  ck_out[t * 3 + 2] = ck2;
  cq_out[t * 3 + 0] = cq0;
  cq_out[t * 3 + 1] = cq1;
  cq_out[t * 3 + 2] = cq2;

  float mean = (cq0 + cq1 + cq2) * (1.f / 3.f);
  float d0 = cq0 - mean, d1 = cq1 - mean, d2 = cq2 - mean;
  float var = (d0 * d0 + d1 * d1 + d2 * d2) * 0.5f;
  float sd  = sqrtf(var);
  float sig = log1pf(__expf(sd));
  float ls  = logf(sig);

  __syncthreads();
  red[tid] = ls;
  __syncthreads();
  for (int r = 128; r > 0; r >>= 1) {
    if (tid < r) red[tid] += red[tid + r];
    __syncthreads();
  }
  if (tid == 0) atomicAdd(loss_acc, red[0]);
}

// ---------------------------------------------------------------------------
// K3: per (bb, lk2): causal 18x18 attention + Wb head + disjoint maxpool.
// ---------------------------------------------------------------------------
__global__ __launch_bounds__(256) void center_kernel(
    const float* __restrict__ cq, const float* __restrict__ ck,
    const float* __restrict__ Wb, const float* __restrict__ bbias,
    float* __restrict__ ccpool) {
  int blk = blockIdx.x;
  int bb  = blk / LK;
  int lk2 = blk % LK;
  int tid = threadIdx.x;

  __shared__ float scq[54], sck[54], sq2[54];
  __shared__ float sWb[3 * 576];
  __shared__ float sbb[576];

  const float* cqb = cq + ((size_t)bb * (LK * B2) + (size_t)lk2 * B2) * 3;
  const float* ckb = ck + ((size_t)bb * (LK * B2) + (size_t)lk2 * B2) * 3;
  if (tid < 54) { scq[tid] = cqb[tid]; sck[tid] = ckb[tid]; }
  for (int i = tid; i < 1728; i += 256) sWb[i] = Wb[i];
  for (int i = tid; i < 576; i += 256) sbb[i] = bbias[i];
  __syncthreads();

  if (tid < B2) {
    int p = tid;
    float s[B2];
    float g0 = scq[p * 3 + 0], g1 = scq[p * 3 + 1], g2 = scq[p * 3 + 2];
    float mx = -INFINITY;
#pragma unroll
    for (int u = 0; u < B2; ++u) {
      float sv = (g0 * sck[u * 3] + g1 * sck[u * 3 + 1] + g2 * sck[u * 3 + 2]) *
                 (1.f / 3.f);
      if (u > p) sv = -1e9f;
      s[u] = sv;
      mx = fmaxf(mx, sv);
    }
    float sum = 0.f;
#pragma unroll
    for (int u = 0; u < B2; ++u) { s[u] = __expf(s[u] - mx); sum += s[u]; }
    float inv = 1.f / sum;
    float o0 = 0.f, o1 = 0.f, o2 = 0.f;
#pragma unroll
    for (int u = 0; u < B2; ++u) {
      float a = s[u] * inv;
      o0 = fmaf(a, scq[u * 3 + 0], o0);
      o1 = fmaf(a, scq[u * 3 + 1], o1);
      o2 = fmaf(a, scq[u * 3 + 2], o2);
    }
    sq2[p * 3 + 0] = o0; sq2[p * 3 + 1] = o1; sq2[p * 3 + 2] = o2;
  }
  __syncthreads();

  float* outb = ccpool + (size_t)bb * CCPOOL_PER_B + (size_t)lk2 * (B2 * 64);
  for (int i = tid; i < B2 * 64; i += 256) {
    int p = i >> 6;
    int w = i & 63;
    float g0 = sq2[p * 3 + 0], g1 = sq2[p * 3 + 1], g2 = sq2[p * 3 + 2];
    int t0 = w * 9 - 4;
    int lo = t0 < 0 ? 0 : t0;
    int hi = t0 + 8; if (hi > 575) hi = 575;
    float mxv = -INFINITY;
    for (int tt = lo; tt <= hi; ++tt) {
      float cv = g0 * sWb[tt] + g1 * sWb[576 + tt] + g2 * sWb[1152 + tt] + sbb[tt];
      cv = fmaxf(cv, 0.f);
      mxv = fmaxf(mxv, cv);
    }
    outb[i] = mxv;
  }
}

// ---------------------------------------------------------------------------
// K4a: prep MFMA operand fragments — bf16 (hi only) of Csum and Vp.
// ---------------------------------------------------------------------------
#define CFRAG_T (NBH*8*3*64)   // 442368
#define VFRAG_T (NBH*5*4*64)   // 368640
__global__ __launch_bounds__(256) void prep_kernel(
    const float* __restrict__ ccpool, const float* __restrict__ pV,
    uint4* __restrict__ Cfrag, uint4* __restrict__ Vfrag) {
  int t = blockIdx.x * 256 + threadIdx.x;   // 811008 exactly
  unsigned short hi[8];
  if (t < CFRAG_T) {
    int lane = t & 63;
    int rest = t >> 6;
    int ks = rest % 3;
    int mtb = rest / 3;
    int mt = mtb & 7;
    int bh = mtb >> 3;
    int bb = bh >> 3, hh = bh & 7;
    int key = mt * 16 + (lane & 15);
    int d0 = ks * 32 + (lane >> 4) * 8;
    const float* cp = ccpool + (size_t)bb * CCPOOL_PER_B + hh * 18432 + key * 72;
#pragma unroll
    for (int j = 0; j < 8; ++j) {
      int d = d0 + j;
      float v = (d < 72) ? (cp[d] + cp[9216 + d]) : 0.f;
      hi[j] = bf16_rne(v);
    }
    uint4 h4;
    h4.x = hi[0] | (hi[1] << 16); h4.y = hi[2] | (hi[3] << 16);
    h4.z = hi[4] | (hi[5] << 16); h4.w = hi[6] | (hi[7] << 16);
    Cfrag[t] = h4;
  } else {
    int t2 = t - CFRAG_T;
    int lane = t2 & 63;
    int rest = t2 >> 6;
    int ks = rest & 3;
    int ntb = rest >> 2;
    int nt = ntb % 5;
    int bh = ntb / 5;
    int d = nt * 16 + (lane & 15);
    int k0 = ks * 32 + (lane >> 4) * 8;
    const float* vp = pV + (size_t)bh * (LK * DK);
#pragma unroll
    for (int j = 0; j < 8; ++j) {
      int k = k0 + j;
      float v = (d < 72) ? vp[k * 72 + d] : 0.f;
      hi[j] = bf16_rne(v);
    }
    uint4 h4;
    h4.x = hi[0] | (hi[1] << 16); h4.y = hi[2] | (hi[3] << 16);
    h4.z = hi[4] | (hi[5] << 16); h4.w = hi[6] | (hi[7] << 16);
    Vfrag[t2] = h4;
  }
}

// ---------------------------------------------------------------------------
// K4b: MFMA attention, zero-LDS version.
// S^T = C_hi * (Q_hi + Q_lo): 2 MFMAs per (s,mt,ks). In-register softmax.
// P transpose to PV A-fragments via ds_bpermute only (q is lane-local in the
// S^T layout; keys move across the four 16-lane groups):
//   target (lq,lg), word c of A-frag at ks comes from
//     src lane = lq + 32*(lg&1) + 16*(c>>1), subtile mt = 2ks+(lg>>1),
//     packed word (c&1).
// O = P * V_hi: 1 MFMA per (s,nt,ks).
// ---------------------------------------------------------------------------
__global__ __launch_bounds__(256) void attn2_kernel(
    const float* __restrict__ Q, const uint4* __restrict__ Cfrag,
    const uint4* __restrict__ Vfrag, float* __restrict__ out) {
  int bh = blockIdx.x / 9, qt = blockIdx.x % 9;
  int wid = threadIdx.x >> 6, lane = threadIdx.x & 63;
  int lq = lane & 15, lg = lane >> 4;
  int qbase = qt * 128 + wid * 32;

  f32x4 sacc[2][8];
#pragma unroll
  for (int s = 0; s < 2; ++s)
#pragma unroll
    for (int mt = 0; mt < 8; ++mt) sacc[s][mt] = (f32x4){0.f, 0.f, 0.f, 0.f};

  // ---- S^T = C * Q^T ----
#pragma unroll
  for (int ks = 0; ks < 3; ++ks) {
    short8 qh[2], ql[2];
#pragma unroll
    for (int s = 0; s < 2; ++s) {
      int q = qbase + s * 16 + lq;
      const float* qrow = Q + ((size_t)bh * L + q) * DK;
      int d0 = ks * 32 + lg * 8;
      float x[8];
      if (ks < 2) {
        float4 a = *(const float4*)(qrow + d0);
        float4 b = *(const float4*)(qrow + d0 + 4);
        x[0] = a.x; x[1] = a.y; x[2] = a.z; x[3] = a.w;
        x[4] = b.x; x[5] = b.y; x[6] = b.z; x[7] = b.w;
      } else {
        if (lg == 0) {
          float4 a = *(const float4*)(qrow + 64);
          float4 b = *(const float4*)(qrow + 68);
          x[0] = a.x; x[1] = a.y; x[2] = a.z; x[3] = a.w;
          x[4] = b.x; x[5] = b.y; x[6] = b.z; x[7] = b.w;
        } else {
#pragma unroll
          for (int j = 0; j < 8; ++j) x[j] = 0.f;
        }
      }
#pragma unroll
      for (int j = 0; j < 8; ++j) {
        unsigned short h, l2;
        split_hl(x[j], h, l2);
        qh[s][j] = (short)h;
        ql[s][j] = (short)l2;
      }
    }
#pragma unroll
    for (int mt = 0; mt < 8; ++mt) {
      short8 chi = *(const short8*)(Cfrag +
          (((size_t)bh * 8 + mt) * 3 + ks) * 64 + lane);
#pragma unroll
      for (int s = 0; s < 2; ++s) {
        sacc[s][mt] = __builtin_amdgcn_mfma_f32_16x16x32_bf16(chi, qh[s], sacc[s][mt], 0, 0, 0);
        sacc[s][mt] = __builtin_amdgcn_mfma_f32_16x16x32_bf16(chi, ql[s], sacc[s][mt], 0, 0, 0);
      }
    }
  }

  // ---- softmax over keys (per q-col), normalized P packed as bf16 pairs ----
  // pw[s][mt][w]: w=0 -> keys 16mt+4lg+{0,1}; w=1 -> +{2,3}; q = lq.
  unsigned pw[2][8][2];
#pragma unroll
  for (int s = 0; s < 2; ++s) {
    float mx = -INFINITY;
#pragma unroll
    for (int mt = 0; mt < 8; ++mt)
#pragma unroll
      for (int r = 0; r < 4; ++r) mx = fmaxf(mx, sacc[s][mt][r]);
    mx = fmaxf(mx, __shfl_xor(mx, 16));
    mx = fmaxf(mx, __shfl_xor(mx, 32));
    float sum = 0.f;
#pragma unroll
    for (int mt = 0; mt < 8; ++mt)
#pragma unroll
      for (int r = 0; r < 4; ++r) {
        float p = __expf(sacc[s][mt][r] - mx);
        sacc[s][mt][r] = p;
        sum += p;
      }
    sum += __shfl_xor(sum, 16);
    sum += __shfl_xor(sum, 32);
    float inv = 1.f / sum;
#pragma unroll
    for (int mt = 0; mt < 8; ++mt) {
      pw[s][mt][0] = pack2(sacc[s][mt][0] * inv, sacc[s][mt][1] * inv);
      pw[s][mt][1] = pack2(sacc[s][mt][2] * inv, sacc[s][mt][3] * inv);
    }
  }

  // ---- O = P * V via bpermute transpose ----
  f32x4 oacc[2][5];
#pragma unroll
  for (int s = 0; s < 2; ++s)
#pragma unroll
    for (int nt = 0; nt < 5; ++nt) oacc[s][nt] = (f32x4){0.f, 0.f, 0.f, 0.f};

  int baseA = lq + 32 * (lg & 1);
  int baseB = baseA + 16;
  bool hiGrp = (lg & 2) != 0;

#pragma unroll
  for (int ks = 0; ks < 4; ++ks) {
    short8 pa[2];
#pragma unroll
    for (int s = 0; s < 2; ++s) {
      unsigned a0 = pw[s][2 * ks][0],     a1 = pw[s][2 * ks][1];
      unsigned b0 = pw[s][2 * ks + 1][0], b1 = pw[s][2 * ks + 1][1];
      unsigned r00 = __shfl(a0, baseA, 64), r10 = __shfl(b0, baseA, 64);
      unsigned r01 = __shfl(a1, baseA, 64), r11 = __shfl(b1, baseA, 64);
      unsigned r02 = __shfl(a0, baseB, 64), r12 = __shfl(b0, baseB, 64);
      unsigned r03 = __shfl(a1, baseB, 64), r13 = __shfl(b1, baseB, 64);
      uint4 u;
      u.x = hiGrp ? r10 : r00;
      u.y = hiGrp ? r11 : r01;
      u.z = hiGrp ? r12 : r02;
      u.w = hiGrp ? r13 : r03;
      pa[s] = *(short8*)&u;
    }
#pragma unroll
    for (int nt = 0; nt < 5; ++nt) {
      short8 vhi = *(const short8*)(Vfrag +
          (((size_t)bh * 5 + nt) * 4 + ks) * 64 + lane);
#pragma unroll
      for (int s = 0; s < 2; ++s) {
        oacc[s][nt] = __builtin_amdgcn_mfma_f32_16x16x32_bf16(pa[s], vhi, oacc[s][nt], 0, 0, 0);
      }
    }
  }

  // ---- store: D layout col=lane&15 (d), row=(lane>>4)*4+r (q) ----
#pragma unroll
  for (int s = 0; s < 2; ++s) {
#pragma unroll
    for (int nt = 0; nt < 5; ++nt) {
      int d = nt * 16 + lq;
      if (d < 72) {
        float* orow = out + ((size_t)bh * L + qbase + s * 16 + lg * 4) * DK + d;
#pragma unroll
        for (int r = 0; r < 4; ++r) orow[(size_t)r * DK] = oacc[s][nt][r];
      }
    }
  }
}

// ---------------------------------------------------------------------------
// K5: finalize loss (mu == xk == 1/3 exactly; ce is a constant).
// ---------------------------------------------------------------------------
__global__ void finalize_kernel(const float* __restrict__ loss_acc,
                                float* __restrict__ out_loss) {
  *out_loss = loss_acc[0] * (1.f / 82944.f) + 207.93889646f;
}

extern "C" void kernel_launch(void* const* d_in, const int* in_sizes, int n_in,
                              void* d_out, int out_size, void* d_ws, size_t ws_size,
                              hipStream_t stream) {
  const float* Q    = (const float*)d_in[0];
  const float* Kin  = (const float*)d_in[1];
  const float* Vin  = (const float*)d_in[2];
  const float* Wp   = (const float*)d_in[3];
  const float* bp   = (const float*)d_in[4];
  const float* Wck  = (const float*)d_in[5];
  const float* bck  = (const float*)d_in[6];
  const float* Wcq  = (const float*)d_in[7];
  const float* bcq  = (const float*)d_in[8];
  const float* Wb   = (const float*)d_in[9];
  const float* bbv  = (const float*)d_in[10];
  float* out = (float*)d_out;

  float* ws = (float*)d_ws;
  float* pK       = ws;
  float* pV       = pK + POOL_TOTAL;
  float* cq       = pV + POOL_TOTAL;
  float* ck       = cq + (size_t)CLUS_TOTAL * 3;
  float* ccpool   = ck + (size_t)CLUS_TOTAL * 3;
  float* cfrag_f  = ccpool + (size_t)BATCH * CCPOOL_PER_B;
  uint4* Cfrag    = (uint4*)cfrag_f;
  uint4* Vfrag    = Cfrag + (size_t)CFRAG_T;
  float* loss_acc = (float*)(Vfrag + (size_t)VFRAG_T);

  hipMemsetAsync(loss_acc, 0, sizeof(float), stream);

  pool_kernel<<<2 * (BATCH * DM) / PROWS, 256, 0, stream>>>(Kin, Vin, pK, pV);
  cluster_kernel<<<BATCH * 9, 256, 0, stream>>>(
      pK, Wp, bp, Wck, bck, Wcq, bcq, cq, ck, loss_acc);
  center_kernel<<<BATCH * LK, 256, 0, stream>>>(cq, ck, Wb, bbv, ccpool);
  prep_kernel<<<(CFRAG_T + VFRAG_T) / 256, 256, 0, stream>>>(ccpool, pV, Cfrag, Vfrag);
  attn2_kernel<<<NBH * 9, 256, 0, stream>>>(Q, Cfrag, Vfrag, out);
  finalize_kernel<<<1, 1, 0, stream>>>(loss_acc, out + CTX_ELEMS);
}